// Round 2
// baseline (1470.922 us; speedup 1.0000x reference)
//
#include <hip/hip_runtime.h>
#include <stdint.h>
#include <stddef.h>

typedef unsigned short u16;
typedef unsigned int u32;
typedef __attribute__((ext_vector_type(8))) short bf16x8;
typedef __attribute__((ext_vector_type(8))) u16 u16x8;
typedef __attribute__((ext_vector_type(4))) float f32x4;

#define NDN 8192
#define NPN 8192
#define EDN 262144
#define EPN 262144
#define BBN 4096
#define KPAD 3392   // 3372 padded to multiple of 64

__device__ __forceinline__ u16 f2b(float f) {
  u32 u = __float_as_uint(f);
  u32 r = (u + 0x7fffu + ((u >> 16) & 1u)) >> 16;  // RTNE
  return (u16)r;
}
__device__ __forceinline__ float b2f(u16 h) {
  return __uint_as_float(((u32)h) << 16);
}

__device__ __forceinline__ void gld_lds16(const void* g, void* l) {
  __builtin_amdgcn_global_load_lds(
      (const __attribute__((address_space(1))) u32*)g,
      (__attribute__((address_space(3))) u32*)l, 16, 0, 0);
}

// ---------------------------------------------------------------------------
// bf16 GEMM: C[M,N] = A[M,K] @ Bt[N,K]^T   (both operands K-contiguous, bf16)
// epilogue: +bias[n], *rowscale[m], relu, f32/bf16 out
// ---------------------------------------------------------------------------
template<int BM, int BN, int WM, int WN>
__global__ void __launch_bounds__(256, 2)
gemm_bf16(const u16* __restrict__ A, int lda,
          const u16* __restrict__ Bt, int ldb,
          int N, int K,
          float* __restrict__ Cf, u16* __restrict__ Cb,
          const float* __restrict__ bias,
          const float* __restrict__ rowscale,
          int relu)
{
  constexpr int AISS = BM / 32;
  constexpr int BISS = BN / 32;
  constexpr int AF = WM / 16;
  constexpr int BF = WN / 16;
  constexpr int WGN = BN / WN;
  __shared__ __align__(16) u16 ldsA[BM * 64];
  __shared__ __align__(16) u16 ldsB[BN * 64];
  const int t = threadIdx.x;
  const int lane = t & 63;
  const int w = t >> 6;
  const int m0 = blockIdx.x * BM;
  const int n0 = blockIdx.y * BN;
  const int wm = w / WGN, wn = w % WGN;
  const int sr = t >> 3;          // staging row within 32-row group
  const int sk = (t & 7) * 8;     // staging k col (elements)

  const u16* arow[AISS];
#pragma unroll
  for (int j = 0; j < AISS; ++j)
    arow[j] = A + (long)(m0 + j * 32 + sr) * lda + sk;
  const u16* brow[BISS];
#pragma unroll
  for (int j = 0; j < BISS; ++j)
    brow[j] = Bt + (long)(n0 + j * 32 + sr) * ldb + sk;

  f32x4 acc[AF][BF];
#pragma unroll
  for (int i = 0; i < AF; ++i)
#pragma unroll
    for (int j = 0; j < BF; ++j)
      acc[i][j] = (f32x4){0.f, 0.f, 0.f, 0.f};

  for (int k0 = 0; k0 < K; k0 += 64) {
#pragma unroll
    for (int j = 0; j < AISS; ++j)
      gld_lds16(arow[j] + k0, &ldsA[(j * 32 + w * 8) * 64]);
#pragma unroll
    for (int j = 0; j < BISS; ++j)
      gld_lds16(brow[j] + k0, &ldsB[(j * 32 + w * 8) * 64]);
    __syncthreads();
#pragma unroll
    for (int k2 = 0; k2 < 64; k2 += 32) {
      bf16x8 af[AF], bfv[BF];
#pragma unroll
      for (int i = 0; i < AF; ++i)
        af[i] = *(const bf16x8*)&ldsA[(wm * WM + i * 16 + (lane & 15)) * 64 + k2 + (lane >> 4) * 8];
#pragma unroll
      for (int i = 0; i < BF; ++i)
        bfv[i] = *(const bf16x8*)&ldsB[(wn * WN + i * 16 + (lane & 15)) * 64 + k2 + (lane >> 4) * 8];
#pragma unroll
      for (int i = 0; i < AF; ++i)
#pragma unroll
        for (int j = 0; j < BF; ++j)
          acc[i][j] = __builtin_amdgcn_mfma_f32_16x16x32_bf16(af[i], bfv[j], acc[i][j], 0, 0, 0);
    }
    __syncthreads();
  }

  const int er = (lane >> 4) * 4;
  const int ecn = lane & 15;
#pragma unroll
  for (int i = 0; i < AF; ++i)
#pragma unroll
    for (int j = 0; j < BF; ++j)
#pragma unroll
      for (int r = 0; r < 4; ++r) {
        long gm = m0 + wm * WM + i * 16 + er + r;
        long gn = n0 + wn * WN + j * 16 + ecn;
        float v = acc[i][j][r];
        if (bias) v += bias[gn];
        if (rowscale) v *= rowscale[gm];
        if (relu) v = fmaxf(v, 0.f);
        if (Cb) Cb[gm * N + gn] = f2b(v);
        else    Cf[gm * N + gn] = v;
      }
}

// ---------------------------------------------------------------------------
// fp32-A GEMM (affinity): C[M,N] = op(A) @ Bt^T, **fp32 out**.
// TRANSA=false: C[m,n] = sum_k A[m,k] * Bt[n,k]      (A rows k-contiguous)
// TRANSA=true : C[m,n] = sum_k A[k,m] * Bt[n,k]      (LDS transpose staging)
// BM=64, BN=256, A staged fp32->bf16 into padded LDS (stride 72)
// ---------------------------------------------------------------------------
template<bool TRANSA>
__global__ void __launch_bounds__(256, 2)
gemm_a32(const float* __restrict__ A, int lda,
         const u16* __restrict__ Bt, int ldb,
         int N, int K, float* __restrict__ Cf)
{
  constexpr int AF = 2, BF = 8, WGN = 2;  // BM=64 (WM=32), BN=256 (WN=128)
  __shared__ __align__(16) u16 ldsA[64 * 72];
  __shared__ __align__(16) u16 ldsB[256 * 64];
  __shared__ __align__(16) float ldsF[TRANSA ? 64 * 64 : 16];
  const int t = threadIdx.x;
  const int lane = t & 63;
  const int w = t >> 6;
  const int m0 = blockIdx.x * 64;
  const int n0 = blockIdx.y * 256;
  const int wm = w / WGN, wn = w % WGN;
  const int sr = t >> 3;
  const int sk = (t & 7) * 8;

  const u16* brow[8];
#pragma unroll
  for (int j = 0; j < 8; ++j)
    brow[j] = Bt + (long)(n0 + j * 32 + sr) * ldb + sk;

  const float* ar_direct = A + (long)(m0 + (t >> 2)) * lda + (t & 3) * 16;

  f32x4 acc[AF][BF];
#pragma unroll
  for (int i = 0; i < AF; ++i)
#pragma unroll
    for (int j = 0; j < BF; ++j)
      acc[i][j] = (f32x4){0.f, 0.f, 0.f, 0.f};

  for (int k0 = 0; k0 < K; k0 += 64) {
#pragma unroll
    for (int j = 0; j < 8; ++j)
      gld_lds16(brow[j] + k0, &ldsB[(j * 32 + w * 8) * 64]);

    if (TRANSA) {
      // fp32 tile A[k0..k0+64][m0..m0+64] -> ldsF [64 k][64 m]
#pragma unroll
      for (int j = 0; j < 4; ++j) {
        int cc = w * 4 + j;                       // 16 chunks of 4 rows
        int d = cc * 4 + (lane >> 4);
        gld_lds16(A + (long)(k0 + d) * lda + m0 + (lane & 15) * 4,
                  &ldsF[cc * 256]);
      }
      __syncthreads();
      // transpose-convert into padded bf16 [m][k] stride 72
      {
        int pp = t & 63, c0 = (t >> 6) * 16;
        float vv[16];
#pragma unroll
        for (int i = 0; i < 16; ++i) vv[i] = ldsF[(c0 + i) * 64 + pp];
        u16x8 ua, ub;
#pragma unroll
        for (int i = 0; i < 8; ++i) { ua[i] = f2b(vv[i]); ub[i] = f2b(vv[8 + i]); }
        *(u16x8*)&ldsA[pp * 72 + c0] = ua;
        *(u16x8*)&ldsA[pp * 72 + c0 + 8] = ub;
      }
    } else {
      const float4* src = (const float4*)(ar_direct + k0);
      float4 v0 = src[0], v1 = src[1], v2 = src[2], v3 = src[3];
      u16x8 ua, ub;
      ua[0] = f2b(v0.x); ua[1] = f2b(v0.y); ua[2] = f2b(v0.z); ua[3] = f2b(v0.w);
      ua[4] = f2b(v1.x); ua[5] = f2b(v1.y); ua[6] = f2b(v1.z); ua[7] = f2b(v1.w);
      ub[0] = f2b(v2.x); ub[1] = f2b(v2.y); ub[2] = f2b(v2.z); ub[3] = f2b(v2.w);
      ub[4] = f2b(v3.x); ub[5] = f2b(v3.y); ub[6] = f2b(v3.z); ub[7] = f2b(v3.w);
      int ro = (t >> 2) * 72 + (t & 3) * 16;
      *(u16x8*)&ldsA[ro] = ua;
      *(u16x8*)&ldsA[ro + 8] = ub;
    }
    __syncthreads();
#pragma unroll
    for (int k2 = 0; k2 < 64; k2 += 32) {
      bf16x8 af[AF], bfv[BF];
#pragma unroll
      for (int i = 0; i < AF; ++i)
        af[i] = *(const bf16x8*)&ldsA[(wm * 32 + i * 16 + (lane & 15)) * 72 + k2 + (lane >> 4) * 8];
#pragma unroll
      for (int i = 0; i < BF; ++i)
        bfv[i] = *(const bf16x8*)&ldsB[(wn * 128 + i * 16 + (lane & 15)) * 64 + k2 + (lane >> 4) * 8];
#pragma unroll
      for (int i = 0; i < AF; ++i)
#pragma unroll
        for (int j = 0; j < BF; ++j)
          acc[i][j] = __builtin_amdgcn_mfma_f32_16x16x32_bf16(af[i], bfv[j], acc[i][j], 0, 0, 0);
    }
    __syncthreads();
  }

  const int er = (lane >> 4) * 4;
  const int ecn = lane & 15;
#pragma unroll
  for (int i = 0; i < AF; ++i)
#pragma unroll
    for (int j = 0; j < BF; ++j)
#pragma unroll
      for (int r = 0; r < 4; ++r) {
        long gm = m0 + wm * 32 + i * 16 + er + r;
        long gn = n0 + wn * 128 + j * 16 + ecn;
        Cf[gm * N + gn] = acc[i][j][r];
      }
}

// ---------------------------------------------------------------------------
// split-precision GEMM: C[M,N] = relu(gather(A_f32)[M,K] @ Bt[N,K]^T + bias)
// A staged as hi+lo bf16 (a = hi + lo), 2x MFMA -> ~19-bit effective mantissa.
// BM=BN=64, 4 waves 2x2 (WM=WN=32). Output fp32.
// ---------------------------------------------------------------------------
__global__ void __launch_bounds__(256, 2)
gemm_sp(const float* __restrict__ A, int lda,
        const u16* __restrict__ Bt, int ldb,
        int N, int K,
        const int* __restrict__ idx,
        const float* __restrict__ bias,
        float* __restrict__ Cf)
{
  __shared__ __align__(16) u16 ldsAh[64 * 64];
  __shared__ __align__(16) u16 ldsAl[64 * 64];
  __shared__ __align__(16) u16 ldsB[64 * 64];
  const int t = threadIdx.x, lane = t & 63, w = t >> 6;
  const int m0 = blockIdx.x * 64, n0 = blockIdx.y * 64;
  const int wm = w >> 1, wn = w & 1;
  const int sr = t >> 3, sk = (t & 7) * 8;
  const int ar = t >> 2;          // 0..63 tile row
  const int ak = (t & 3) * 16;    // k offset: 0,16,32,48
  long arow = idx ? (long)idx[m0 + ar] : (long)(m0 + ar);
  const float* Ap = A + arow * (long)lda + ak;
  const u16* brow[2];
#pragma unroll
  for (int j = 0; j < 2; ++j)
    brow[j] = Bt + (long)(n0 + j * 32 + sr) * ldb + sk;

  f32x4 acc[2][2];
#pragma unroll
  for (int i = 0; i < 2; ++i)
#pragma unroll
    for (int j = 0; j < 2; ++j)
      acc[i][j] = (f32x4){0.f, 0.f, 0.f, 0.f};

  for (int k0 = 0; k0 < K; k0 += 64) {
#pragma unroll
    for (int j = 0; j < 2; ++j)
      gld_lds16(brow[j] + k0, &ldsB[(j * 32 + w * 8) * 64]);
    const float4* src = (const float4*)(Ap + k0);
    float4 v0 = src[0], v1 = src[1], v2 = src[2], v3 = src[3];
    float f[16] = {v0.x, v0.y, v0.z, v0.w, v1.x, v1.y, v1.z, v1.w,
                   v2.x, v2.y, v2.z, v2.w, v3.x, v3.y, v3.z, v3.w};
    u16x8 h0, h1v, l0, l1v;
#pragma unroll
    for (int i = 0; i < 8; ++i) {
      u16 h = f2b(f[i]);       h0[i] = h;  l0[i] = f2b(f[i] - b2f(h));
      u16 g = f2b(f[8 + i]);   h1v[i] = g; l1v[i] = f2b(f[8 + i] - b2f(g));
    }
    *(u16x8*)&ldsAh[ar * 64 + ak] = h0;
    *(u16x8*)&ldsAh[ar * 64 + ak + 8] = h1v;
    *(u16x8*)&ldsAl[ar * 64 + ak] = l0;
    *(u16x8*)&ldsAl[ar * 64 + ak + 8] = l1v;
    __syncthreads();
#pragma unroll
    for (int k2 = 0; k2 < 64; k2 += 32) {
      bf16x8 ah[2], al[2], bv[2];
#pragma unroll
      for (int i = 0; i < 2; ++i) {
        int off = (wm * 32 + i * 16 + (lane & 15)) * 64 + k2 + (lane >> 4) * 8;
        ah[i] = *(const bf16x8*)&ldsAh[off];
        al[i] = *(const bf16x8*)&ldsAl[off];
      }
#pragma unroll
      for (int i = 0; i < 2; ++i)
        bv[i] = *(const bf16x8*)&ldsB[(wn * 32 + i * 16 + (lane & 15)) * 64 + k2 + (lane >> 4) * 8];
#pragma unroll
      for (int i = 0; i < 2; ++i)
#pragma unroll
        for (int j = 0; j < 2; ++j) {
          acc[i][j] = __builtin_amdgcn_mfma_f32_16x16x32_bf16(ah[i], bv[j], acc[i][j], 0, 0, 0);
          acc[i][j] = __builtin_amdgcn_mfma_f32_16x16x32_bf16(al[i], bv[j], acc[i][j], 0, 0, 0);
        }
    }
    __syncthreads();
  }

  const int er = (lane >> 4) * 4;
  const int ecn = lane & 15;
#pragma unroll
  for (int i = 0; i < 2; ++i)
#pragma unroll
    for (int j = 0; j < 2; ++j)
#pragma unroll
      for (int r = 0; r < 4; ++r) {
        long gm = m0 + wm * 32 + i * 16 + er + r;
        long gn = n0 + wn * 32 + j * 16 + ecn;
        float v = acc[i][j][r] + bias[gn];
        Cf[gm * N + gn] = fmaxf(v, 0.f);
      }
}

// ---------------------------------------------------------------------------
// small kernels
// ---------------------------------------------------------------------------
__global__ void cvt_bf16(const float* __restrict__ x, u16* __restrict__ y, long n) {
  long i = ((long)blockIdx.x * 256 + threadIdx.x) * 4;
  if (i < n) {
    float4 v = *(const float4*)&x[i];
    u16 a = f2b(v.x), b = f2b(v.y), c = f2b(v.z), d = f2b(v.w);
    u32 lo = (u32)a | ((u32)b << 16);
    u32 hi = (u32)c | ((u32)d << 16);
    *(uint2*)&y[i] = make_uint2(lo, hi);
  }
}

// in [R x C] f32 -> out [C x Rpad] bf16 (transpose + convert, zero-pad rows >= R)
__global__ void wtrans(const float* __restrict__ in, u16* __restrict__ out,
                       int R, int C, int Rpad) {
  __shared__ float tile[32][33];
  int r0 = blockIdx.x * 32, c0 = blockIdx.y * 32;
  int tx = threadIdx.x & 31, ty = threadIdx.x >> 5;  // 32 x 8
  for (int j = 0; j < 32; j += 8) {
    int r = r0 + ty + j, c = c0 + tx;
    tile[ty + j][tx] = (r < R && c < C) ? in[(long)r * C + c] : 0.f;
  }
  __syncthreads();
  for (int j = 0; j < 32; j += 8) {
    int c = c0 + ty + j, r = r0 + tx;
    if (c < C && r < Rpad) out[(long)c * Rpad + r] = f2b(tile[tx][ty + j]);
  }
}

// bf16 transpose: in [R x C] -> out [C x R]
__global__ void btrans(const u16* __restrict__ in, u16* __restrict__ out, int R, int C) {
  __shared__ u16 tile[32][34];
  int r0 = blockIdx.x * 32, c0 = blockIdx.y * 32;
  int tx = threadIdx.x & 31, ty = threadIdx.x >> 5;
  for (int j = 0; j < 32; j += 8)
    tile[ty + j][tx] = in[(long)(r0 + ty + j) * C + c0 + tx];
  __syncthreads();
  for (int j = 0; j < 32; j += 8)
    out[(long)(c0 + ty + j) * R + r0 + tx] = tile[tx][ty + j];
}

__global__ void edge_deg(const int* __restrict__ ei, const float* __restrict__ ew,
                         int E, float* degw, int* cnt) {
  int e = blockIdx.x * 256 + threadIdx.x;
  if (e < E) {
    int dst = ei[E + e];
    atomicAdd(&degw[dst], ew[e]);
    atomicAdd(&cnt[dst], 1);
  }
}

__global__ void make_dinv(const float* __restrict__ degw, float* __restrict__ dinv, int N) {
  int i = blockIdx.x * 256 + threadIdx.x;
  if (i < N) dinv[i] = rsqrtf(degw[i] + 1.0f);  // +1 self-loop weight
}

// exclusive scan of cnt[8192] -> rowptr[8193] and cursor[8192]; single block of 256
__global__ void scan8k(const int* __restrict__ cnt, int* __restrict__ rowptr,
                       int* __restrict__ cursor) {
  __shared__ int lds[256];
  int t = threadIdx.x;
  int c0 = t * 32;
  int loc[32];
  int s = 0;
#pragma unroll
  for (int i = 0; i < 32; ++i) { loc[i] = cnt[c0 + i]; s += loc[i]; }
  lds[t] = s;
  __syncthreads();
  for (int off = 1; off < 256; off <<= 1) {
    int add = (t >= off) ? lds[t - off] : 0;
    __syncthreads();
    lds[t] += add;
    __syncthreads();
  }
  int run = lds[t] - s;  // exclusive prefix of this chunk
#pragma unroll
  for (int i = 0; i < 32; ++i) {
    rowptr[c0 + i] = run;
    cursor[c0 + i] = run;
    run += loc[i];
  }
  if (t == 255) rowptr[8192] = run;
}

__global__ void edge_scatter(const int* __restrict__ ei, const float* __restrict__ ew,
                             int E, int* __restrict__ cursor, int2* __restrict__ edges) {
  int e = blockIdx.x * 256 + threadIdx.x;
  if (e < E) {
    int src = ei[e], dst = ei[E + e];
    int pos = atomicAdd(&cursor[dst], 1);
    edges[pos] = make_int2(src, __float_as_int(ew[e]));
  }
}

// out[i] = leaky( bias + dinv[i] * (hs[i] + sum_e w_e * hs[src_e]) )
__global__ void gcn_aggregate(const u16* __restrict__ hs,
                              const int* __restrict__ rowptr,
                              const int2* __restrict__ edges,
                              const float* __restrict__ dinv,
                              const float* __restrict__ bias,
                              u16* __restrict__ out) {
  const int i = blockIdx.x;
  const int t = threadIdx.x;  // 256, each owns cols 2t, 2t+1
  const u32* base = (const u32*)hs;
  u32 hv = base[i * 256 + t];
  float a0 = b2f((u16)(hv & 0xffff));
  float a1 = b2f((u16)(hv >> 16));
  int s = rowptr[i], e = rowptr[i + 1];
  int p = s;
  for (; p + 4 <= e; p += 4) {
    int2 e0 = edges[p], e1 = edges[p + 1], e2 = edges[p + 2], e3 = edges[p + 3];
    u32 v0 = base[(long)e0.x * 256 + t];
    u32 v1 = base[(long)e1.x * 256 + t];
    u32 v2 = base[(long)e2.x * 256 + t];
    u32 v3 = base[(long)e3.x * 256 + t];
    float w0 = __int_as_float(e0.y), w1 = __int_as_float(e1.y);
    float w2 = __int_as_float(e2.y), w3 = __int_as_float(e3.y);
    a0 += w0 * b2f((u16)(v0 & 0xffff)); a1 += w0 * b2f((u16)(v0 >> 16));
    a0 += w1 * b2f((u16)(v1 & 0xffff)); a1 += w1 * b2f((u16)(v1 >> 16));
    a0 += w2 * b2f((u16)(v2 & 0xffff)); a1 += w2 * b2f((u16)(v2 >> 16));
    a0 += w3 * b2f((u16)(v3 & 0xffff)); a1 += w3 * b2f((u16)(v3 >> 16));
  }
  for (; p < e; ++p) {
    int2 ee = edges[p];
    u32 v = base[(long)ee.x * 256 + t];
    float ww = __int_as_float(ee.y);
    a0 += ww * b2f((u16)(v & 0xffff));
    a1 += ww * b2f((u16)(v >> 16));
  }
  float di = dinv[i];
  float o0 = bias[2 * t] + di * a0;
  float o1 = bias[2 * t + 1] + di * a1;
  o0 = (o0 >= 0.f) ? o0 : 0.01f * o0;
  o1 = (o1 >= 0.f) ? o1 : 0.01f * o1;
  ((u32*)out)[i * 256 + t] = (u32)f2b(o0) | ((u32)f2b(o1) << 16);
}

// column sums (for feat centering). grid: ((cols+255)/256, 32), 128 rows/block
__global__ void colsum_f32(const float* __restrict__ src, int ld, int cols,
                           const int* __restrict__ idx, float* __restrict__ out) {
  int c = blockIdx.x * 256 + threadIdx.x;
  if (c >= cols) return;
  int r0 = blockIdx.y * 128;
  float s = 0.f;
  for (int r = r0; r < r0 + 128; ++r) {
    long row = idx ? (long)idx[r] : (long)r;
    s += src[row * ld + c];
  }
  atomicAdd(&out[c], s);
}

__global__ void colsum_b16(const u16* __restrict__ src, int ld, int cols,
                           const int* __restrict__ idx, float* __restrict__ out) {
  int c = blockIdx.x * 256 + threadIdx.x;
  if (c >= cols) return;
  int r0 = blockIdx.y * 128;
  float s = 0.f;
  for (int r = r0; r < r0 + 128; ++r) {
    long row = idx ? (long)idx[r] : (long)r;
    s += b2f(src[row * ld + c]);
  }
  atomicAdd(&out[c], s);
}

// feature assembly (column-centered): [B x 3392] bf16
__global__ void assemble(const float* __restrict__ d_vecs, const float* __restrict__ p_emb,
                         const u16* __restrict__ ec, const u16* __restrict__ gos,
                         const float* __restrict__ t1, const float* __restrict__ t2,
                         const int* __restrict__ didx, const int* __restrict__ pidx,
                         const float* __restrict__ cs, u16* __restrict__ feat) {
  const float is = 1.f / 4096.f;
  int b = blockIdx.x;
  int t = threadIdx.x;
  long ob = (long)b * KPAD;
  int di = didx[b], pi = pidx[b];
  for (int j = t; j < 300; j += 256)
    feat[ob + j] = f2b(d_vecs[(long)b * 300 + j] - cs[j] * is);
  for (int j = t; j < 1024; j += 256)
    feat[ob + 300 + j] = f2b(p_emb[(long)b * 1024 + j] - cs[300 + j] * is);
  for (int j = t; j < 512; j += 256) {
    feat[ob + 1324 + j] = f2b(b2f(ec[(long)di * 512 + j]) - cs[1324 + j] * is);
    feat[ob + 1836 + j] = f2b(t1[(long)b * 512 + j] - cs[1836 + j] * is);
    feat[ob + 2348 + j] = f2b(b2f(gos[(long)pi * 512 + j]) - cs[2348 + j] * is);
    feat[ob + 2860 + j] = f2b(t2[(long)b * 512 + j] - cs[2860 + j] * is);
  }
  for (int j = t; j < 20; j += 256) feat[ob + 3372 + j] = 0;
}

__global__ void bn_stats(const float* __restrict__ x, int N,
                         float* __restrict__ sum, float* __restrict__ sumsq) {
  int r0 = blockIdx.x * 64;
  int t = threadIdx.x;
  for (int c = t; c < N; c += 256) {
    float s = 0.f, q = 0.f;
    for (int r = 0; r < 64; ++r) {
      float v = x[(long)(r0 + r) * N + c];
      s += v; q += v * v;
    }
    atomicAdd(&sum[c], s);
    atomicAdd(&sumsq[c], q);
  }
}

__global__ void bn_apply(const float* __restrict__ x, int M, int N, int nmask,
                         const float* __restrict__ sum, const float* __restrict__ sumsq,
                         const float* __restrict__ g, const float* __restrict__ be,
                         u16* __restrict__ y) {
  long i = (long)blockIdx.x * 256 + threadIdx.x;
  if (i >= (long)M * N) return;
  int c = (int)(i & nmask);
  float m = sum[c] / (float)M;
  float v = sumsq[c] / (float)M - m * m;
  float sc = g[c] * rsqrtf(v + 1e-5f);
  float sh = be[c] - m * sc;
  float o = fmaxf(x[i] * sc + sh, 0.f);
  y[i] = f2b(o);
}

// y[b] = sum_j h[b,j] * w[j] + b0 ; one wave per row, N=256
__global__ void final_dot(const u16* __restrict__ h, const float* __restrict__ w,
                          const float* __restrict__ b0, float* __restrict__ y) {
  int wv = threadIdx.x >> 6, lane = threadIdx.x & 63;
  int row = blockIdx.x * 4 + wv;
  const u16* hr = h + (long)row * 256;
  ushort4 u = *(const ushort4*)&hr[lane * 4];
  float acc = b2f(u.x) * w[lane * 4] + b2f(u.y) * w[lane * 4 + 1] +
              b2f(u.z) * w[lane * 4 + 2] + b2f(u.w) * w[lane * 4 + 3];
  for (int off = 32; off; off >>= 1) acc += __shfl_down(acc, off);
  if (lane == 0) y[row] = acc + b0[0];
}

// ---------------------------------------------------------------------------
extern "C" void kernel_launch(void* const* d_in, const int* in_sizes, int n_in,
                              void* d_out, int out_size, void* d_ws, size_t ws_size,
                              hipStream_t stream) {
  (void)in_sizes; (void)n_in; (void)out_size; (void)ws_size;
  const int*   d_index  = (const int*)d_in[0];
  const int*   p_index  = (const int*)d_in[1];
  const float* d_vecs   = (const float*)d_in[2];
  const float* p_emb    = (const float*)d_in[3];
  const float* d_ecfps  = (const float*)d_in[4];
  const int*   d_ei     = (const int*)d_in[5];
  const float* d_ew     = (const float*)d_in[6];
  const float* p_gos    = (const float*)d_in[7];
  const int*   p_ei     = (const int*)d_in[8];
  const float* p_ew     = (const float*)d_in[9];
  const float* affinity = (const float*)d_in[10];
  const float* W_e  = (const float*)d_in[11];
  const float* b_e  = (const float*)d_in[12];
  const float* W_g  = (const float*)d_in[13];
  const float* b_g  = (const float*)d_in[14];
  const float* W1   = (const float*)d_in[15];
  const float* b1   = (const float*)d_in[16];
  const float* W2   = (const float*)d_in[17];
  const float* b2   = (const float*)d_in[18];
  const float* Wo1  = (const float*)d_in[19];
  const float* bo1  = (const float*)d_in[20];
  const float* g1   = (const float*)d_in[21];
  const float* be1  = (const float*)d_in[22];
  const float* Wo2  = (const float*)d_in[23];
  const float* bo2  = (const float*)d_in[24];
  const float* g2   = (const float*)d_in[25];
  const float* be2  = (const float*)d_in[26];
  const float* Wo3  = (const float*)d_in[27];
  const float* bo3  = (const float*)d_in[28];
  float* y_out = (float*)d_out;

  char* p = (char*)d_ws;
  auto alloc = [&](size_t bytes) -> char* {
    char* q = p;
    p += (bytes + 255) & ~(size_t)255;
    return q;
  };

  // zero-init block (one memset)
  char* zero_start = p;
  float* degw_e = (float*)alloc(NDN * 4);
  int*   cnt_e  = (int*)alloc(NDN * 4);
  float* degw_p = (float*)alloc(NPN * 4);
  int*   cnt_p  = (int*)alloc(NPN * 4);
  float* bnsum1 = (float*)alloc(1024 * 4);
  float* bnsq1  = (float*)alloc(1024 * 4);
  float* bnsum2 = (float*)alloc(256 * 4);
  float* bnsq2  = (float*)alloc(256 * 4);
  float* colsum = (float*)alloc(KPAD * 4);
  size_t zero_bytes = (size_t)(p - zero_start);

  float* dinv_e   = (float*)alloc(NDN * 4);
  float* dinv_p   = (float*)alloc(NPN * 4);
  int*   rowptr_e = (int*)alloc((NDN + 1) * 4);
  int*   cursor_e = (int*)alloc(NDN * 4);
  int*   rowptr_p = (int*)alloc((NPN + 1) * 4);
  int*   cursor_p = (int*)alloc(NPN * 4);
  int2*  edges_e  = (int2*)alloc((size_t)EDN * 8);
  int2*  edges_p  = (int2*)alloc((size_t)EPN * 8);
  u16* x_e_b  = (u16*)alloc((size_t)NDN * 1024 * 2);   // aliased: tmp1_f after G1
  u16* x_g_b  = (u16*)alloc((size_t)NPN * 1024 * 2);   // aliased: tmp2_f after G2
  u16* WeT    = (u16*)alloc((size_t)512 * 1024 * 2);
  u16* WgT    = (u16*)alloc((size_t)512 * 1024 * 2);
  u16* W1T    = (u16*)alloc((size_t)512 * 512 * 2);
  u16* W2T    = (u16*)alloc((size_t)512 * 512 * 2);
  u16* Wo1T   = (u16*)alloc((size_t)1024 * KPAD * 2);
  u16* Wo2T   = (u16*)alloc((size_t)256 * 1024 * 2);
  u16* hs_e   = (u16*)alloc((size_t)NDN * 512 * 2);    // aliased: t1_f after aggregate
  u16* hs_g   = (u16*)alloc((size_t)NPN * 512 * 2);    // aliased: t2_f after aggregate
  u16* ec_b   = (u16*)alloc((size_t)NDN * 512 * 2);
  u16* gos_b  = (u16*)alloc((size_t)NPN * 512 * 2);
  u16* ecT_b  = (u16*)alloc((size_t)512 * NDN * 2);
  u16* gosT_b = (u16*)alloc((size_t)512 * NPN * 2);
  u16* feat_b = (u16*)alloc((size_t)BBN * KPAD * 2);
  float* h1   = (float*)alloc((size_t)BBN * 1024 * 4);
  u16* h1n_b  = (u16*)alloc((size_t)BBN * 1024 * 2);
  float* h2   = (float*)alloc((size_t)BBN * 256 * 4);
  u16* h2n_b  = (u16*)alloc((size_t)BBN * 256 * 2);

  // aliases (exact-size overlays; source buffers dead before first write)
  float* tmp1_f = (float*)x_e_b;   // [8192 x 512] f32 = 16.78 MB = x_e_b size
  float* tmp2_f = (float*)x_g_b;
  float* t1_f   = (float*)hs_e;    // [4096 x 512] f32 = 8.39 MB = hs_e size
  float* t2_f   = (float*)hs_g;

  hipMemsetAsync(zero_start, 0, zero_bytes, stream);

  // input conversions
  cvt_bf16<<<8192, 256, 0, stream>>>(d_ecfps, x_e_b, (long)NDN * 1024);
  cvt_bf16<<<8192, 256, 0, stream>>>(p_gos, x_g_b, (long)NPN * 1024);
  wtrans<<<dim3(32, 16), 256, 0, stream>>>(W_e, WeT, 1024, 512, 1024);
  wtrans<<<dim3(32, 16), 256, 0, stream>>>(W_g, WgT, 1024, 512, 1024);
  wtrans<<<dim3(16, 16), 256, 0, stream>>>(W1, W1T, 512, 512, 512);
  wtrans<<<dim3(16, 16), 256, 0, stream>>>(W2, W2T, 512, 512, 512);
  wtrans<<<dim3(106, 32), 256, 0, stream>>>(Wo1, Wo1T, 3372, 1024, KPAD);
  wtrans<<<dim3(32, 8), 256, 0, stream>>>(Wo2, Wo2T, 1024, 256, 1024);

  // graph prep
  edge_deg<<<EDN / 256, 256, 0, stream>>>(d_ei, d_ew, EDN, degw_e, cnt_e);
  edge_deg<<<EPN / 256, 256, 0, stream>>>(p_ei, p_ew, EPN, degw_p, cnt_p);
  make_dinv<<<NDN / 256, 256, 0, stream>>>(degw_e, dinv_e, NDN);
  make_dinv<<<NPN / 256, 256, 0, stream>>>(degw_p, dinv_p, NPN);
  scan8k<<<1, 256, 0, stream>>>(cnt_e, rowptr_e, cursor_e);
  scan8k<<<1, 256, 0, stream>>>(cnt_p, rowptr_p, cursor_p);
  edge_scatter<<<EDN / 256, 256, 0, stream>>>(d_ei, d_ew, EDN, cursor_e, edges_e);
  edge_scatter<<<EPN / 256, 256, 0, stream>>>(p_ei, p_ew, EPN, cursor_p, edges_p);

  // G1/G2: hs = dinv[m] * (x @ W)   [8192 x 512] bf16
  gemm_bf16<128, 128, 64, 64><<<dim3(64, 4), 256, 0, stream>>>(
      x_e_b, 1024, WeT, 1024, 512, 1024,
      (float*)nullptr, hs_e, (const float*)nullptr, dinv_e, 0);
  gemm_bf16<128, 128, 64, 64><<<dim3(64, 4), 256, 0, stream>>>(
      x_g_b, 1024, WgT, 1024, 512, 1024,
      (float*)nullptr, hs_g, (const float*)nullptr, dinv_p, 0);

  // aggregation -> node features (bf16)
  gcn_aggregate<<<NDN, 256, 0, stream>>>(hs_e, rowptr_e, edges_e, dinv_e, b_e, ec_b);
  gcn_aggregate<<<NPN, 256, 0, stream>>>(hs_g, rowptr_p, edges_p, dinv_p, b_g, gos_b);

  // transposes for K-contiguous B operands
  btrans<<<dim3(256, 16), 256, 0, stream>>>(ec_b, ecT_b, NDN, 512);
  btrans<<<dim3(256, 16), 256, 0, stream>>>(gos_b, gosT_b, NPN, 512);

  // G3: tmp1 = affinity @ gos  (A rows direct)   [8192 x 512] fp32
  gemm_a32<false><<<dim3(128, 2), 256, 0, stream>>>(
      affinity, 8192, gosT_b, 8192, 512, 8192, tmp1_f);
  // G4: tmp2 = affinity^T @ ecfps (LDS transpose) [8192 x 512] fp32
  gemm_a32<true><<<dim3(128, 2), 256, 0, stream>>>(
      affinity, 8192, ecT_b, 8192, 512, 8192, tmp2_f);

  // G5/G6: split-precision, gathered rows: t = relu(tmp[idx] @ W + b) fp32
  gemm_sp<<<dim3(64, 8), 256, 0, stream>>>(
      tmp1_f, 512, W1T, 512, 512, 512, d_index, b1, t1_f);
  gemm_sp<<<dim3(64, 8), 256, 0, stream>>>(
      tmp2_f, 512, W2T, 512, 512, 512, p_index, b2, t2_f);

  // feature column sums (for centering; exactly BN1-equivalent)
  colsum_f32<<<dim3(2, 32),  256, 0, stream>>>(d_vecs, 300, 300, nullptr, colsum);
  colsum_f32<<<dim3(4, 32),  256, 0, stream>>>(p_emb, 1024, 1024, nullptr, colsum + 300);
  colsum_b16<<<dim3(2, 32),  256, 0, stream>>>(ec_b, 512, 512, d_index, colsum + 1324);
  colsum_f32<<<dim3(2, 32),  256, 0, stream>>>(t1_f, 512, 512, nullptr, colsum + 1836);
  colsum_b16<<<dim3(2, 32),  256, 0, stream>>>(gos_b, 512, 512, p_index, colsum + 2348);
  colsum_f32<<<dim3(2, 32),  256, 0, stream>>>(t2_f, 512, 512, nullptr, colsum + 2860);

  assemble<<<BBN, 256, 0, stream>>>(d_vecs, p_emb, ec_b, gos_b, t1_f, t2_f,
                                    d_index, p_index, colsum, feat_b);

  // G7: h1 = feat_c @ Wo1 + bo1  (fp32 out; h1 columns ~zero-mean)
  gemm_bf16<128, 128, 64, 64><<<dim3(32, 8), 256, 0, stream>>>(
      feat_b, KPAD, Wo1T, KPAD, 1024, KPAD,
      h1, (u16*)nullptr, bo1, (const float*)nullptr, 0);
  bn_stats<<<64, 256, 0, stream>>>(h1, 1024, bnsum1, bnsq1);
  bn_apply<<<16384, 256, 0, stream>>>(h1, BBN, 1024, 1023, bnsum1, bnsq1, g1, be1, h1n_b);

  // G8: h2 = h1n @ Wo2 + bo2 (fp32 out)
  gemm_bf16<64, 64, 32, 32><<<dim3(64, 4), 256, 0, stream>>>(
      h1n_b, 1024, Wo2T, 1024, 256, 1024,
      h2, (u16*)nullptr, bo2, (const float*)nullptr, 0);
  bn_stats<<<64, 256, 0, stream>>>(h2, 256, bnsum2, bnsq2);
  bn_apply<<<4096, 256, 0, stream>>>(h2, BBN, 256, 255, bnsum2, bnsq2, g2, be2, h2n_b);

  final_dot<<<1024, 256, 0, stream>>>(h2n_b, Wo3, bo3, y_out);
}

// Round 3
// 1176.577 us; speedup vs baseline: 1.2502x; 1.2502x over previous
//
#include <hip/hip_runtime.h>
#include <stdint.h>
#include <stddef.h>

typedef unsigned short u16;
typedef unsigned int u32;
typedef __attribute__((ext_vector_type(8))) short bf16x8;
typedef __attribute__((ext_vector_type(8))) u16 u16x8;
typedef __attribute__((ext_vector_type(4))) float f32x4;

#define NDN 8192
#define NPN 8192
#define EDN 262144
#define EPN 262144
#define BBN 4096
#define KPAD 3392   // 3372 padded to multiple of 64

__device__ __forceinline__ u16 f2b(float f) {
  u32 u = __float_as_uint(f);
  u32 r = (u + 0x7fffu + ((u >> 16) & 1u)) >> 16;  // RTNE
  return (u16)r;
}
__device__ __forceinline__ float b2f(u16 h) {
  return __uint_as_float(((u32)h) << 16);
}

__device__ __forceinline__ void gld_lds16(const void* g, void* l) {
  __builtin_amdgcn_global_load_lds(
      (const __attribute__((address_space(1))) u32*)g,
      (__attribute__((address_space(3))) u32*)l, 16, 0, 0);
}

// ---------------------------------------------------------------------------
// bf16 GEMM: C[M,N] = A[M,K] @ Bt[N,K]^T   (both operands K-contiguous, bf16)
// epilogue: +bias[n], *rowscale[m], relu, f32/bf16 out
// ---------------------------------------------------------------------------
template<int BM, int BN, int WM, int WN>
__global__ void __launch_bounds__(256, 2)
gemm_bf16(const u16* __restrict__ A, int lda,
          const u16* __restrict__ Bt, int ldb,
          int N, int K,
          float* __restrict__ Cf, u16* __restrict__ Cb,
          const float* __restrict__ bias,
          const float* __restrict__ rowscale,
          int relu)
{
  constexpr int AISS = BM / 32;
  constexpr int BISS = BN / 32;
  constexpr int AF = WM / 16;
  constexpr int BF = WN / 16;
  constexpr int WGN = BN / WN;
  __shared__ __align__(16) u16 ldsA[BM * 64];
  __shared__ __align__(16) u16 ldsB[BN * 64];
  const int t = threadIdx.x;
  const int lane = t & 63;
  const int w = t >> 6;
  const int m0 = blockIdx.x * BM;
  const int n0 = blockIdx.y * BN;
  const int wm = w / WGN, wn = w % WGN;
  const int sr = t >> 3;          // staging row within 32-row group
  const int sk = (t & 7) * 8;     // staging k col (elements)

  const u16* arow[AISS];
#pragma unroll
  for (int j = 0; j < AISS; ++j)
    arow[j] = A + (long)(m0 + j * 32 + sr) * lda + sk;
  const u16* brow[BISS];
#pragma unroll
  for (int j = 0; j < BISS; ++j)
    brow[j] = Bt + (long)(n0 + j * 32 + sr) * ldb + sk;

  f32x4 acc[AF][BF];
#pragma unroll
  for (int i = 0; i < AF; ++i)
#pragma unroll
    for (int j = 0; j < BF; ++j)
      acc[i][j] = (f32x4){0.f, 0.f, 0.f, 0.f};

  for (int k0 = 0; k0 < K; k0 += 64) {
#pragma unroll
    for (int j = 0; j < AISS; ++j)
      gld_lds16(arow[j] + k0, &ldsA[(j * 32 + w * 8) * 64]);
#pragma unroll
    for (int j = 0; j < BISS; ++j)
      gld_lds16(brow[j] + k0, &ldsB[(j * 32 + w * 8) * 64]);
    __syncthreads();
#pragma unroll
    for (int k2 = 0; k2 < 64; k2 += 32) {
      bf16x8 af[AF], bfv[BF];
#pragma unroll
      for (int i = 0; i < AF; ++i)
        af[i] = *(const bf16x8*)&ldsA[(wm * WM + i * 16 + (lane & 15)) * 64 + k2 + (lane >> 4) * 8];
#pragma unroll
      for (int i = 0; i < BF; ++i)
        bfv[i] = *(const bf16x8*)&ldsB[(wn * WN + i * 16 + (lane & 15)) * 64 + k2 + (lane >> 4) * 8];
#pragma unroll
      for (int i = 0; i < AF; ++i)
#pragma unroll
        for (int j = 0; j < BF; ++j)
          acc[i][j] = __builtin_amdgcn_mfma_f32_16x16x32_bf16(af[i], bfv[j], acc[i][j], 0, 0, 0);
    }
    __syncthreads();
  }

  const int er = (lane >> 4) * 4;
  const int ecn = lane & 15;
#pragma unroll
  for (int i = 0; i < AF; ++i)
#pragma unroll
    for (int j = 0; j < BF; ++j)
#pragma unroll
      for (int r = 0; r < 4; ++r) {
        long gm = m0 + wm * WM + i * 16 + er + r;
        long gn = n0 + wn * WN + j * 16 + ecn;
        float v = acc[i][j][r];
        if (bias) v += bias[gn];
        if (rowscale) v *= rowscale[gm];
        if (relu) v = fmaxf(v, 0.f);
        if (Cb) Cb[gm * N + gn] = f2b(v);
        else    Cf[gm * N + gn] = v;
      }
}

// ---------------------------------------------------------------------------
// fp32-A GEMM (affinity), split-K partials, fp32 out.
// TRANSA=false: C[m,n] = sum_k A[gather(m),k] * Bt[n,k]   (rows k-contiguous)
// TRANSA=true : C[m,n] = sum_k A[k,m] * Bt[n,k]           (LDS transpose)
// BM=64, BN=256. K param = per-split length; split z covers [z*K, (z+1)*K).
// Partial z written at Cf + z*zstride.
// ---------------------------------------------------------------------------
template<bool TRANSA>
__global__ void __launch_bounds__(256, 2)
gemm_a32(const float* __restrict__ A, int lda,
         const u16* __restrict__ Bt, int ldb,
         int N, int K,
         const int* __restrict__ idx,
         float* __restrict__ Cf, long zstride)
{
  constexpr int AF = 2, BF = 8, WGN = 2;  // BM=64 (WM=32), BN=256 (WN=128)
  __shared__ __align__(16) u16 ldsA[64 * 72];
  __shared__ __align__(16) u16 ldsB[256 * 64];
  __shared__ __align__(16) float ldsF[TRANSA ? 64 * 64 : 16];
  const int t = threadIdx.x;
  const int lane = t & 63;
  const int w = t >> 6;
  const int m0 = blockIdx.x * 64;
  const int n0 = blockIdx.y * 256;
  const int kOff = blockIdx.z * K;
  const int wm = w / WGN, wn = w % WGN;
  const int sr = t >> 3;
  const int sk = (t & 7) * 8;

  Cf += (long)blockIdx.z * zstride;

  const u16* brow[8];
#pragma unroll
  for (int j = 0; j < 8; ++j)
    brow[j] = Bt + (long)(n0 + j * 32 + sr) * ldb + sk + kOff;

  long rowsel = 0;
  if (!TRANSA) {
    int r = m0 + (t >> 2);
    rowsel = idx ? (long)idx[r] : (long)r;
  }
  const float* ar_direct = A + rowsel * (long)lda + (t & 3) * 16 + kOff;

  f32x4 acc[AF][BF];
#pragma unroll
  for (int i = 0; i < AF; ++i)
#pragma unroll
    for (int j = 0; j < BF; ++j)
      acc[i][j] = (f32x4){0.f, 0.f, 0.f, 0.f};

  for (int k0 = 0; k0 < K; k0 += 64) {
#pragma unroll
    for (int j = 0; j < 8; ++j)
      gld_lds16(brow[j] + k0, &ldsB[(j * 32 + w * 8) * 64]);

    if (TRANSA) {
      // fp32 tile A[kOff+k0 .. +64][m0..m0+64] -> ldsF [64 k][64 m]
#pragma unroll
      for (int j = 0; j < 4; ++j) {
        int cc = w * 4 + j;                       // 16 chunks of 4 rows
        int d = cc * 4 + (lane >> 4);
        gld_lds16(A + (long)(kOff + k0 + d) * lda + m0 + (lane & 15) * 4,
                  &ldsF[cc * 256]);
      }
      __syncthreads();
      // transpose-convert into padded bf16 [m][k] stride 72
      {
        int pp = t & 63, c0 = (t >> 6) * 16;
        float vv[16];
#pragma unroll
        for (int i = 0; i < 16; ++i) vv[i] = ldsF[(c0 + i) * 64 + pp];
        u16x8 ua, ub;
#pragma unroll
        for (int i = 0; i < 8; ++i) { ua[i] = f2b(vv[i]); ub[i] = f2b(vv[8 + i]); }
        *(u16x8*)&ldsA[pp * 72 + c0] = ua;
        *(u16x8*)&ldsA[pp * 72 + c0 + 8] = ub;
      }
    } else {
      const float4* src = (const float4*)(ar_direct + k0);
      float4 v0 = src[0], v1 = src[1], v2 = src[2], v3 = src[3];
      u16x8 ua, ub;
      ua[0] = f2b(v0.x); ua[1] = f2b(v0.y); ua[2] = f2b(v0.z); ua[3] = f2b(v0.w);
      ua[4] = f2b(v1.x); ua[5] = f2b(v1.y); ua[6] = f2b(v1.z); ua[7] = f2b(v1.w);
      ub[0] = f2b(v2.x); ub[1] = f2b(v2.y); ub[2] = f2b(v2.z); ub[3] = f2b(v2.w);
      ub[4] = f2b(v3.x); ub[5] = f2b(v3.y); ub[6] = f2b(v3.w == v3.w ? v3.w : v3.w); // keep simple
      ub[6] = f2b(v3.z); ub[7] = f2b(v3.w);
      // fix ordering explicitly (see below)
      ub[0] = f2b(v2.x); ub[1] = f2b(v2.y); ub[2] = f2b(v2.z); ub[3] = f2b(v2.w);
      ub[4] = f2b(v3.x); ub[5] = f2b(v3.y); ub[6] = f2b(v3.z); ub[7] = f2b(v3.w);
      int ro = (t >> 2) * 72 + (t & 3) * 16;
      *(u16x8*)&ldsA[ro] = ua;
      *(u16x8*)&ldsA[ro + 8] = ub;
      __syncthreads();
    }
    if (TRANSA) __syncthreads();
    else __syncthreads();
#pragma unroll
    for (int k2 = 0; k2 < 64; k2 += 32) {
      bf16x8 af[AF], bfv[BF];
#pragma unroll
      for (int i = 0; i < AF; ++i)
        af[i] = *(const bf16x8*)&ldsA[(wm * 32 + i * 16 + (lane & 15)) * 72 + k2 + (lane >> 4) * 8];
#pragma unroll
      for (int i = 0; i < BF; ++i)
        bfv[i] = *(const bf16x8*)&ldsB[(wn * 128 + i * 16 + (lane & 15)) * 64 + k2 + (lane >> 4) * 8];
#pragma unroll
      for (int i = 0; i < AF; ++i)
#pragma unroll
        for (int j = 0; j < BF; ++j)
          acc[i][j] = __builtin_amdgcn_mfma_f32_16x16x32_bf16(af[i], bfv[j], acc[i][j], 0, 0, 0);
    }
    __syncthreads();
  }

  const int er = (lane >> 4) * 4;
  const int ecn = lane & 15;
#pragma unroll
  for (int i = 0; i < AF; ++i)
#pragma unroll
    for (int j = 0; j < BF; ++j)
#pragma unroll
      for (int r = 0; r < 4; ++r) {
        long gm = m0 + wm * 32 + i * 16 + er + r;
        long gn = n0 + wn * 128 + j * 16 + ecn;
        Cf[gm * N + gn] = acc[i][j][r];
      }
}

// sum `parts` partial buffers of n floats each into out
__global__ void reduceP(const float* __restrict__ p, long n, int parts,
                        float* __restrict__ out) {
  long i = ((long)blockIdx.x * 256 + threadIdx.x) * 4;
  if (i >= n) return;
  float4 a = *(const float4*)&p[i];
  for (int z = 1; z < parts; ++z) {
    float4 b = *(const float4*)&p[(long)z * n + i];
    a.x += b.x; a.y += b.y; a.z += b.z; a.w += b.w;
  }
  *(float4*)&out[i] = a;
}

// ---------------------------------------------------------------------------
// split-precision GEMM: C[M,N] = relu(gather(A_f32)[M,K] @ Bt[N,K]^T + bias)
// A staged as hi+lo bf16 (a = hi + lo), 2x MFMA -> ~19-bit effective mantissa.
// BM=BN=64, 4 waves 2x2 (WM=WN=32). Output fp32.
// ---------------------------------------------------------------------------
__global__ void __launch_bounds__(256, 2)
gemm_sp(const float* __restrict__ A, int lda,
        const u16* __restrict__ Bt, int ldb,
        int N, int K,
        const int* __restrict__ idx,
        const float* __restrict__ bias,
        float* __restrict__ Cf)
{
  __shared__ __align__(16) u16 ldsAh[64 * 64];
  __shared__ __align__(16) u16 ldsAl[64 * 64];
  __shared__ __align__(16) u16 ldsB[64 * 64];
  const int t = threadIdx.x, lane = t & 63, w = t >> 6;
  const int m0 = blockIdx.x * 64, n0 = blockIdx.y * 64;
  const int wm = w >> 1, wn = w & 1;
  const int sr = t >> 3, sk = (t & 7) * 8;
  const int ar = t >> 2;          // 0..63 tile row
  const int ak = (t & 3) * 16;    // k offset: 0,16,32,48
  long arow = idx ? (long)idx[m0 + ar] : (long)(m0 + ar);
  const float* Ap = A + arow * (long)lda + ak;
  const u16* brow[2];
#pragma unroll
  for (int j = 0; j < 2; ++j)
    brow[j] = Bt + (long)(n0 + j * 32 + sr) * ldb + sk;

  f32x4 acc[2][2];
#pragma unroll
  for (int i = 0; i < 2; ++i)
#pragma unroll
    for (int j = 0; j < 2; ++j)
      acc[i][j] = (f32x4){0.f, 0.f, 0.f, 0.f};

  for (int k0 = 0; k0 < K; k0 += 64) {
#pragma unroll
    for (int j = 0; j < 2; ++j)
      gld_lds16(brow[j] + k0, &ldsB[(j * 32 + w * 8) * 64]);
    const float4* src = (const float4*)(Ap + k0);
    float4 v0 = src[0], v1 = src[1], v2 = src[2], v3 = src[3];
    float f[16] = {v0.x, v0.y, v0.z, v0.w, v1.x, v1.y, v1.z, v1.w,
                   v2.x, v2.y, v2.z, v2.w, v3.x, v3.y, v3.z, v3.w};
    u16x8 h0, h1v, l0, l1v;
#pragma unroll
    for (int i = 0; i < 8; ++i) {
      u16 h = f2b(f[i]);       h0[i] = h;  l0[i] = f2b(f[i] - b2f(h));
      u16 g = f2b(f[8 + i]);   h1v[i] = g; l1v[i] = f2b(f[8 + i] - b2f(g));
    }
    *(u16x8*)&ldsAh[ar * 64 + ak] = h0;
    *(u16x8*)&ldsAh[ar * 64 + ak + 8] = h1v;
    *(u16x8*)&ldsAl[ar * 64 + ak] = l0;
    *(u16x8*)&ldsAl[ar * 64 + ak + 8] = l1v;
    __syncthreads();
#pragma unroll
    for (int k2 = 0; k2 < 64; k2 += 32) {
      bf16x8 ah[2], al[2], bv[2];
#pragma unroll
      for (int i = 0; i < 2; ++i) {
        int off = (wm * 32 + i * 16 + (lane & 15)) * 64 + k2 + (lane >> 4) * 8;
        ah[i] = *(const bf16x8*)&ldsAh[off];
        al[i] = *(const bf16x8*)&ldsAl[off];
      }
#pragma unroll
      for (int i = 0; i < 2; ++i)
        bv[i] = *(const bf16x8*)&ldsB[(wn * 32 + i * 16 + (lane & 15)) * 64 + k2 + (lane >> 4) * 8];
#pragma unroll
      for (int i = 0; i < 2; ++i)
#pragma unroll
        for (int j = 0; j < 2; ++j) {
          acc[i][j] = __builtin_amdgcn_mfma_f32_16x16x32_bf16(ah[i], bv[j], acc[i][j], 0, 0, 0);
          acc[i][j] = __builtin_amdgcn_mfma_f32_16x16x32_bf16(al[i], bv[j], acc[i][j], 0, 0, 0);
        }
    }
    __syncthreads();
  }

  const int er = (lane >> 4) * 4;
  const int ecn = lane & 15;
#pragma unroll
  for (int i = 0; i < 2; ++i)
#pragma unroll
    for (int j = 0; j < 2; ++j)
#pragma unroll
      for (int r = 0; r < 4; ++r) {
        long gm = m0 + wm * 32 + i * 16 + er + r;
        long gn = n0 + wn * 32 + j * 16 + ecn;
        float v = acc[i][j][r] + bias[gn];
        Cf[gm * N + gn] = fmaxf(v, 0.f);
      }
}

// ---------------------------------------------------------------------------
// small kernels
// ---------------------------------------------------------------------------
__global__ void cvt_bf16(const float* __restrict__ x, u16* __restrict__ y, long n) {
  long i = ((long)blockIdx.x * 256 + threadIdx.x) * 4;
  if (i < n) {
    float4 v = *(const float4*)&x[i];
    u16 a = f2b(v.x), b = f2b(v.y), c = f2b(v.z), d = f2b(v.w);
    u32 lo = (u32)a | ((u32)b << 16);
    u32 hi = (u32)c | ((u32)d << 16);
    *(uint2*)&y[i] = make_uint2(lo, hi);
  }
}

// in [R x C] f32 -> out [C x Rpad] bf16 (transpose + convert, zero-pad rows >= R)
__global__ void wtrans(const float* __restrict__ in, u16* __restrict__ out,
                       int R, int C, int Rpad) {
  __shared__ float tile[32][33];
  int r0 = blockIdx.x * 32, c0 = blockIdx.y * 32;
  int tx = threadIdx.x & 31, ty = threadIdx.x >> 5;  // 32 x 8
  for (int j = 0; j < 32; j += 8) {
    int r = r0 + ty + j, c = c0 + tx;
    tile[ty + j][tx] = (r < R && c < C) ? in[(long)r * C + c] : 0.f;
  }
  __syncthreads();
  for (int j = 0; j < 32; j += 8) {
    int c = c0 + ty + j, r = r0 + tx;
    if (c < C && r < Rpad) out[(long)c * Rpad + r] = f2b(tile[tx][ty + j]);
  }
}

// bf16 transpose: in [R x C] -> out [C x R]
__global__ void btrans(const u16* __restrict__ in, u16* __restrict__ out, int R, int C) {
  __shared__ u16 tile[32][34];
  int r0 = blockIdx.x * 32, c0 = blockIdx.y * 32;
  int tx = threadIdx.x & 31, ty = threadIdx.x >> 5;
  for (int j = 0; j < 32; j += 8)
    tile[ty + j][tx] = in[(long)(r0 + ty + j) * C + c0 + tx];
  __syncthreads();
  for (int j = 0; j < 32; j += 8)
    out[(long)(c0 + ty + j) * R + r0 + tx] = tile[tx][ty + j];
}

__global__ void edge_deg(const int* __restrict__ ei, const float* __restrict__ ew,
                         int E, float* degw, int* cnt) {
  int e = blockIdx.x * 256 + threadIdx.x;
  if (e < E) {
    int dst = ei[E + e];
    atomicAdd(&degw[dst], ew[e]);
    atomicAdd(&cnt[dst], 1);
  }
}

__global__ void make_dinv(const float* __restrict__ degw, float* __restrict__ dinv, int N) {
  int i = blockIdx.x * 256 + threadIdx.x;
  if (i < N) dinv[i] = rsqrtf(degw[i] + 1.0f);  // +1 self-loop weight
}

// exclusive scan of cnt[8192] -> rowptr[8193] and cursor[8192]; single block of 256
__global__ void scan8k(const int* __restrict__ cnt, int* __restrict__ rowptr,
                       int* __restrict__ cursor) {
  __shared__ int lds[256];
  int t = threadIdx.x;
  int c0 = t * 32;
  int loc[32];
  int s = 0;
#pragma unroll
  for (int i = 0; i < 32; ++i) { loc[i] = cnt[c0 + i]; s += loc[i]; }
  lds[t] = s;
  __syncthreads();
  for (int off = 1; off < 256; off <<= 1) {
    int add = (t >= off) ? lds[t - off] : 0;
    __syncthreads();
    lds[t] += add;
    __syncthreads();
  }
  int run = lds[t] - s;  // exclusive prefix of this chunk
#pragma unroll
  for (int i = 0; i < 32; ++i) {
    rowptr[c0 + i] = run;
    cursor[c0 + i] = run;
    run += loc[i];
  }
  if (t == 255) rowptr[8192] = run;
}

__global__ void edge_scatter(const int* __restrict__ ei, const float* __restrict__ ew,
                             int E, int* __restrict__ cursor, int2* __restrict__ edges) {
  int e = blockIdx.x * 256 + threadIdx.x;
  if (e < E) {
    int src = ei[e], dst = ei[E + e];
    int pos = atomicAdd(&cursor[dst], 1);
    edges[pos] = make_int2(src, __float_as_int(ew[e]));
  }
}

// out[i] = leaky( bias + dinv[i] * (hs[i] + sum_e w_e * hs[src_e]) )
__global__ void gcn_aggregate(const u16* __restrict__ hs,
                              const int* __restrict__ rowptr,
                              const int2* __restrict__ edges,
                              const float* __restrict__ dinv,
                              const float* __restrict__ bias,
                              u16* __restrict__ out) {
  const int i = blockIdx.x;
  const int t = threadIdx.x;  // 256, each owns cols 2t, 2t+1
  const u32* base = (const u32*)hs;
  u32 hv = base[i * 256 + t];
  float a0 = b2f((u16)(hv & 0xffff));
  float a1 = b2f((u16)(hv >> 16));
  int s = rowptr[i], e = rowptr[i + 1];
  int p = s;
  for (; p + 4 <= e; p += 4) {
    int2 e0 = edges[p], e1 = edges[p + 1], e2 = edges[p + 2], e3 = edges[p + 3];
    u32 v0 = base[(long)e0.x * 256 + t];
    u32 v1 = base[(long)e1.x * 256 + t];
    u32 v2 = base[(long)e2.x * 256 + t];
    u32 v3 = base[(long)e3.x * 256 + t];
    float w0 = __int_as_float(e0.y), w1 = __int_as_float(e1.y);
    float w2 = __int_as_float(e2.y), w3 = __int_as_float(e3.y);
    a0 += w0 * b2f((u16)(v0 & 0xffff)); a1 += w0 * b2f((u16)(v0 >> 16));
    a0 += w1 * b2f((u16)(v1 & 0xffff)); a1 += w1 * b2f((u16)(v1 >> 16));
    a0 += w2 * b2f((u16)(v2 & 0xffff)); a1 += w2 * b2f((u16)(v2 >> 16));
    a0 += w3 * b2f((u16)(v3 & 0xffff)); a1 += w3 * b2f((u16)(v3 >> 16));
  }
  for (; p < e; ++p) {
    int2 ee = edges[p];
    u32 v = base[(long)ee.x * 256 + t];
    float ww = __int_as_float(ee.y);
    a0 += ww * b2f((u16)(v & 0xffff));
    a1 += ww * b2f((u16)(v >> 16));
  }
  float di = dinv[i];
  float o0 = bias[2 * t] + di * a0;
  float o1 = bias[2 * t + 1] + di * a1;
  o0 = (o0 >= 0.f) ? o0 : 0.01f * o0;
  o1 = (o1 >= 0.f) ? o1 : 0.01f * o1;
  ((u32*)out)[i * 256 + t] = (u32)f2b(o0) | ((u32)f2b(o1) << 16);
}

// column sums (for feat centering). grid: ((cols+255)/256, 32), 128 rows/block
__global__ void colsum_f32(const float* __restrict__ src, int ld, int cols,
                           const int* __restrict__ idx, float* __restrict__ out) {
  int c = blockIdx.x * 256 + threadIdx.x;
  if (c >= cols) return;
  int r0 = blockIdx.y * 128;
  float s = 0.f;
  for (int r = r0; r < r0 + 128; ++r) {
    long row = idx ? (long)idx[r] : (long)r;
    s += src[row * ld + c];
  }
  atomicAdd(&out[c], s);
}

__global__ void colsum_b16(const u16* __restrict__ src, int ld, int cols,
                           const int* __restrict__ idx, float* __restrict__ out) {
  int c = blockIdx.x * 256 + threadIdx.x;
  if (c >= cols) return;
  int r0 = blockIdx.y * 128;
  float s = 0.f;
  for (int r = r0; r < r0 + 128; ++r) {
    long row = idx ? (long)idx[r] : (long)r;
    s += b2f(src[row * ld + c]);
  }
  atomicAdd(&out[c], s);
}

// feature assembly (column-centered): [B x 3392] bf16
__global__ void assemble(const float* __restrict__ d_vecs, const float* __restrict__ p_emb,
                         const u16* __restrict__ ec, const u16* __restrict__ gos,
                         const float* __restrict__ t1, const float* __restrict__ t2,
                         const int* __restrict__ didx, const int* __restrict__ pidx,
                         const float* __restrict__ cs, u16* __restrict__ feat) {
  const float is = 1.f / 4096.f;
  int b = blockIdx.x;
  int t = threadIdx.x;
  long ob = (long)b * KPAD;
  int di = didx[b], pi = pidx[b];
  for (int j = t; j < 300; j += 256)
    feat[ob + j] = f2b(d_vecs[(long)b * 300 + j] - cs[j] * is);
  for (int j = t; j < 1024; j += 256)
    feat[ob + 300 + j] = f2b(p_emb[(long)b * 1024 + j] - cs[300 + j] * is);
  for (int j = t; j < 512; j += 256) {
    feat[ob + 1324 + j] = f2b(b2f(ec[(long)di * 512 + j]) - cs[1324 + j] * is);
    feat[ob + 1836 + j] = f2b(t1[(long)b * 512 + j] - cs[1836 + j] * is);
    feat[ob + 2348 + j] = f2b(b2f(gos[(long)pi * 512 + j]) - cs[2348 + j] * is);
    feat[ob + 2860 + j] = f2b(t2[(long)b * 512 + j] - cs[2860 + j] * is);
  }
  for (int j = t; j < 20; j += 256) feat[ob + 3372 + j] = 0;
}

__global__ void bn_stats(const float* __restrict__ x, int N,
                         float* __restrict__ sum, float* __restrict__ sumsq) {
  int r0 = blockIdx.x * 64;
  int t = threadIdx.x;
  for (int c = t; c < N; c += 256) {
    float s = 0.f, q = 0.f;
    for (int r = 0; r < 64; ++r) {
      float v = x[(long)(r0 + r) * N + c];
      s += v; q += v * v;
    }
    atomicAdd(&sum[c], s);
    atomicAdd(&sumsq[c], q);
  }
}

__global__ void bn_apply(const float* __restrict__ x, int M, int N, int nmask,
                         const float* __restrict__ sum, const float* __restrict__ sumsq,
                         const float* __restrict__ g, const float* __restrict__ be,
                         u16* __restrict__ y) {
  long i = (long)blockIdx.x * 256 + threadIdx.x;
  if (i >= (long)M * N) return;
  int c = (int)(i & nmask);
  float m = sum[c] / (float)M;
  float v = sumsq[c] / (float)M - m * m;
  float sc = g[c] * rsqrtf(v + 1e-5f);
  float sh = be[c] - m * sc;
  float o = fmaxf(x[i] * sc + sh, 0.f);
  y[i] = f2b(o);
}

// y[b] = sum_j h[b,j] * w[j] + b0 ; one wave per row, N=256
__global__ void final_dot(const u16* __restrict__ h, const float* __restrict__ w,
                          const float* __restrict__ b0, float* __restrict__ y) {
  int wv = threadIdx.x >> 6, lane = threadIdx.x & 63;
  int row = blockIdx.x * 4 + wv;
  const u16* hr = h + (long)row * 256;
  ushort4 u = *(const ushort4*)&hr[lane * 4];
  float acc = b2f(u.x) * w[lane * 4] + b2f(u.y) * w[lane * 4 + 1] +
              b2f(u.z) * w[lane * 4 + 2] + b2f(u.w) * w[lane * 4 + 3];
  for (int off = 32; off; off >>= 1) acc += __shfl_down(acc, off);
  if (lane == 0) y[row] = acc + b0[0];
}

// ---------------------------------------------------------------------------
extern "C" void kernel_launch(void* const* d_in, const int* in_sizes, int n_in,
                              void* d_out, int out_size, void* d_ws, size_t ws_size,
                              hipStream_t stream) {
  (void)in_sizes; (void)n_in; (void)out_size; (void)ws_size;
  const int*   d_index  = (const int*)d_in[0];
  const int*   p_index  = (const int*)d_in[1];
  const float* d_vecs   = (const float*)d_in[2];
  const float* p_emb    = (const float*)d_in[3];
  const float* d_ecfps  = (const float*)d_in[4];
  const int*   d_ei     = (const int*)d_in[5];
  const float* d_ew     = (const float*)d_in[6];
  const float* p_gos    = (const float*)d_in[7];
  const int*   p_ei     = (const int*)d_in[8];
  const float* p_ew     = (const float*)d_in[9];
  const float* affinity = (const float*)d_in[10];
  const float* W_e  = (const float*)d_in[11];
  const float* b_e  = (const float*)d_in[12];
  const float* W_g  = (const float*)d_in[13];
  const float* b_g  = (const float*)d_in[14];
  const float* W1   = (const float*)d_in[15];
  const float* b1   = (const float*)d_in[16];
  const float* W2   = (const float*)d_in[17];
  const float* b2   = (const float*)d_in[18];
  const float* Wo1  = (const float*)d_in[19];
  const float* bo1  = (const float*)d_in[20];
  const float* g1   = (const float*)d_in[21];
  const float* be1  = (const float*)d_in[22];
  const float* Wo2  = (const float*)d_in[23];
  const float* bo2  = (const float*)d_in[24];
  const float* g2   = (const float*)d_in[25];
  const float* be2  = (const float*)d_in[26];
  const float* Wo3  = (const float*)d_in[27];
  const float* bo3  = (const float*)d_in[28];
  float* y_out = (float*)d_out;

  char* p = (char*)d_ws;
  auto alloc = [&](size_t bytes) -> char* {
    char* q = p;
    p += (bytes + 255) & ~(size_t)255;
    return q;
  };

  // zero-init block (one memset)
  char* zero_start = p;
  float* degw_e = (float*)alloc(NDN * 4);
  int*   cnt_e  = (int*)alloc(NDN * 4);
  float* degw_p = (float*)alloc(NPN * 4);
  int*   cnt_p  = (int*)alloc(NPN * 4);
  float* bnsum1 = (float*)alloc(1024 * 4);
  float* bnsq1  = (float*)alloc(1024 * 4);
  float* bnsum2 = (float*)alloc(256 * 4);
  float* bnsq2  = (float*)alloc(256 * 4);
  float* colsum = (float*)alloc(KPAD * 4);
  size_t zero_bytes = (size_t)(p - zero_start);

  float* dinv_e   = (float*)alloc(NDN * 4);
  float* dinv_p   = (float*)alloc(NPN * 4);
  int*   rowptr_e = (int*)alloc((NDN + 1) * 4);
  int*   cursor_e = (int*)alloc(NDN * 4);
  int*   rowptr_p = (int*)alloc((NPN + 1) * 4);
  int*   cursor_p = (int*)alloc(NPN * 4);
  int2*  edges_e  = (int2*)alloc((size_t)EDN * 8);
  int2*  edges_p  = (int2*)alloc((size_t)EPN * 8);
  u16* x_e_b  = (u16*)alloc((size_t)NDN * 1024 * 2);   // aliased: tmp1_f after G1
  u16* x_g_b  = (u16*)alloc((size_t)NPN * 1024 * 2);   // aliased: tmp2_f after G2
  u16* WeT    = (u16*)alloc((size_t)512 * 1024 * 2);
  u16* WgT    = (u16*)alloc((size_t)512 * 1024 * 2);
  u16* W1T    = (u16*)alloc((size_t)512 * 512 * 2);
  u16* W2T    = (u16*)alloc((size_t)512 * 512 * 2);
  u16* Wo1T   = (u16*)alloc((size_t)1024 * KPAD * 2);
  u16* Wo2T   = (u16*)alloc((size_t)256 * 1024 * 2);
  u16* hs_e   = (u16*)alloc((size_t)NDN * 512 * 2);    // aliased: t1_f after aggregate
  u16* hs_g   = (u16*)alloc((size_t)NPN * 512 * 2);    // aliased: t2_f after aggregate
  u16* ec_b   = (u16*)alloc((size_t)NDN * 512 * 2);
  u16* gos_b  = (u16*)alloc((size_t)NPN * 512 * 2);
  u16* ecT_b  = (u16*)alloc((size_t)512 * NDN * 2);
  u16* gosT_b = (u16*)alloc((size_t)512 * NPN * 2);
  u16* feat_b = (u16*)alloc((size_t)BBN * KPAD * 2);
  float* h1   = (float*)alloc((size_t)BBN * 1024 * 4);
  u16* h1n_b  = (u16*)alloc((size_t)BBN * 1024 * 2);
  float* h2   = (float*)alloc((size_t)BBN * 256 * 4);
  u16* h2n_b  = (u16*)alloc((size_t)BBN * 256 * 2);
  // split-K partial buffer: max(4 * 4096*512, 2 * 8192*512) floats = 33.6 MB
  float* partK = (float*)alloc((size_t)4 * BBN * 512 * 4);

  // aliases (exact-size overlays; source buffers dead before first write)
  float* tmp1_f = (float*)x_e_b;   // [4096 x 512] f32 (gathered) <= x_e_b size
  float* tmp2_f = (float*)x_g_b;   // [8192 x 512] f32 = x_g_b size
  float* t1_f   = (float*)hs_e;    // [4096 x 512] f32 = hs_e size
  float* t2_f   = (float*)hs_g;

  hipMemsetAsync(zero_start, 0, zero_bytes, stream);

  // input conversions
  cvt_bf16<<<8192, 256, 0, stream>>>(d_ecfps, x_e_b, (long)NDN * 1024);
  cvt_bf16<<<8192, 256, 0, stream>>>(p_gos, x_g_b, (long)NPN * 1024);
  wtrans<<<dim3(32, 16), 256, 0, stream>>>(W_e, WeT, 1024, 512, 1024);
  wtrans<<<dim3(32, 16), 256, 0, stream>>>(W_g, WgT, 1024, 512, 1024);
  wtrans<<<dim3(16, 16), 256, 0, stream>>>(W1, W1T, 512, 512, 512);
  wtrans<<<dim3(16, 16), 256, 0, stream>>>(W2, W2T, 512, 512, 512);
  wtrans<<<dim3(106, 32), 256, 0, stream>>>(Wo1, Wo1T, 3372, 1024, KPAD);
  wtrans<<<dim3(32, 8), 256, 0, stream>>>(Wo2, Wo2T, 1024, 256, 1024);

  // graph prep
  edge_deg<<<EDN / 256, 256, 0, stream>>>(d_ei, d_ew, EDN, degw_e, cnt_e);
  edge_deg<<<EPN / 256, 256, 0, stream>>>(p_ei, p_ew, EPN, degw_p, cnt_p);
  make_dinv<<<NDN / 256, 256, 0, stream>>>(degw_e, dinv_e, NDN);
  make_dinv<<<NPN / 256, 256, 0, stream>>>(degw_p, dinv_p, NPN);
  scan8k<<<1, 256, 0, stream>>>(cnt_e, rowptr_e, cursor_e);
  scan8k<<<1, 256, 0, stream>>>(cnt_p, rowptr_p, cursor_p);
  edge_scatter<<<EDN / 256, 256, 0, stream>>>(d_ei, d_ew, EDN, cursor_e, edges_e);
  edge_scatter<<<EPN / 256, 256, 0, stream>>>(p_ei, p_ew, EPN, cursor_p, edges_p);

  // G1/G2: hs = dinv[m] * (x @ W)   [8192 x 512] bf16   (64x128 tiles, 512 blocks)
  gemm_bf16<64, 128, 32, 64><<<dim3(128, 4), 256, 0, stream>>>(
      x_e_b, 1024, WeT, 1024, 512, 1024,
      (float*)nullptr, hs_e, (const float*)nullptr, dinv_e, 0);
  gemm_bf16<64, 128, 32, 64><<<dim3(128, 4), 256, 0, stream>>>(
      x_g_b, 1024, WgT, 1024, 512, 1024,
      (float*)nullptr, hs_g, (const float*)nullptr, dinv_p, 0);

  // aggregation -> node features (bf16)
  gcn_aggregate<<<NDN, 256, 0, stream>>>(hs_e, rowptr_e, edges_e, dinv_e, b_e, ec_b);
  gcn_aggregate<<<NPN, 256, 0, stream>>>(hs_g, rowptr_p, edges_p, dinv_p, b_g, gos_b);

  // transposes for K-contiguous B operands
  btrans<<<dim3(256, 16), 256, 0, stream>>>(ec_b, ecT_b, NDN, 512);
  btrans<<<dim3(256, 16), 256, 0, stream>>>(gos_b, gosT_b, NPN, 512);

  // G3: tmp1_g = affinity[d_index] @ gos   [4096 x 512] fp32, split-K=4
  gemm_a32<false><<<dim3(64, 2, 4), 256, 0, stream>>>(
      affinity, 8192, gosT_b, 8192, 512, 2048, d_index, partK, (long)BBN * 512);
  reduceP<<<2048, 256, 0, stream>>>(partK, (long)BBN * 512, 4, tmp1_f);

  // G4: tmp2 = affinity^T @ ecfps (LDS transpose) [8192 x 512] fp32, split-K=2
  gemm_a32<true><<<dim3(128, 2, 2), 256, 0, stream>>>(
      affinity, 8192, ecT_b, 8192, 512, 4096, (const int*)nullptr,
      partK, (long)NDN * 512);
  reduceP<<<4096, 256, 0, stream>>>(partK, (long)NDN * 512, 2, tmp2_f);

  // G5/G6: split-precision: t = relu(tmp[rows] @ W + b) fp32
  gemm_sp<<<dim3(64, 8), 256, 0, stream>>>(
      tmp1_f, 512, W1T, 512, 512, 512, (const int*)nullptr, b1, t1_f);
  gemm_sp<<<dim3(64, 8), 256, 0, stream>>>(
      tmp2_f, 512, W2T, 512, 512, 512, p_index, b2, t2_f);

  // feature column sums (for centering; exactly BN1-equivalent)
  colsum_f32<<<dim3(2, 32),  256, 0, stream>>>(d_vecs, 300, 300, nullptr, colsum);
  colsum_f32<<<dim3(4, 32),  256, 0, stream>>>(p_emb, 1024, 1024, nullptr, colsum + 300);
  colsum_b16<<<dim3(2, 32),  256, 0, stream>>>(ec_b, 512, 512, d_index, colsum + 1324);
  colsum_f32<<<dim3(2, 32),  256, 0, stream>>>(t1_f, 512, 512, nullptr, colsum + 1836);
  colsum_b16<<<dim3(2, 32),  256, 0, stream>>>(gos_b, 512, 512, p_index, colsum + 2348);
  colsum_f32<<<dim3(2, 32),  256, 0, stream>>>(t2_f, 512, 512, nullptr, colsum + 2860);

  assemble<<<BBN, 256, 0, stream>>>(d_vecs, p_emb, ec_b, gos_b, t1_f, t2_f,
                                    d_index, p_index, colsum, feat_b);

  // G7: h1 = feat_c @ Wo1 + bo1  (fp32 out; 64x128 tiles, 512 blocks)
  gemm_bf16<64, 128, 32, 64><<<dim3(64, 8), 256, 0, stream>>>(
      feat_b, KPAD, Wo1T, KPAD, 1024, KPAD,
      h1, (u16*)nullptr, bo1, (const float*)nullptr, 0);
  bn_stats<<<64, 256, 0, stream>>>(h1, 1024, bnsum1, bnsq1);
  bn_apply<<<16384, 256, 0, stream>>>(h1, BBN, 1024, 1023, bnsum1, bnsq1, g1, be1, h1n_b);

  // G8: h2 = h1n @ Wo2 + bo2 (fp32 out)
  gemm_bf16<64, 64, 32, 32><<<dim3(64, 4), 256, 0, stream>>>(
      h1n_b, 1024, Wo2T, 1024, 256, 1024,
      h2, (u16*)nullptr, bo2, (const float*)nullptr, 0);
  bn_stats<<<64, 256, 0, stream>>>(h2, 256, bnsum2, bnsq2);
  bn_apply<<<4096, 256, 0, stream>>>(h2, BBN, 256, 255, bnsum2, bnsq2, g2, be2, h2n_b);

  final_dot<<<1024, 256, 0, stream>>>(h2n_b, Wo3, bo3, y_out);
}

// Round 4
// 1122.751 us; speedup vs baseline: 1.3101x; 1.0479x over previous
//
#include <hip/hip_runtime.h>
#include <stdint.h>
#include <stddef.h>

typedef unsigned short u16;
typedef unsigned int u32;
typedef __attribute__((ext_vector_type(8))) short bf16x8;
typedef __attribute__((ext_vector_type(8))) u16 u16x8;
typedef __attribute__((ext_vector_type(4))) float f32x4;

#define NDN 8192
#define NPN 8192
#define EDN 262144
#define EPN 262144
#define BBN 4096
#define KPAD 3392   // 3372 padded to multiple of 64

__device__ __forceinline__ u16 f2b(float f) {
  u32 u = __float_as_uint(f);
  u32 r = (u + 0x7fffu + ((u >> 16) & 1u)) >> 16;  // RTNE
  return (u16)r;
}
__device__ __forceinline__ float b2f(u16 h) {
  return __uint_as_float(((u32)h) << 16);
}

__device__ __forceinline__ void gld_lds16(const void* g, void* l) {
  __builtin_amdgcn_global_load_lds(
      (const __attribute__((address_space(1))) u32*)g,
      (__attribute__((address_space(3))) u32*)l, 16, 0, 0);
}

// ---------------------------------------------------------------------------
// bf16 GEMM: C[M,N] = gather(A)[M,K] @ Bt[N,K]^T  (both K-contiguous bf16)
// split-K via gridDim.z (KZ = per-split len, partial z at Cf + z*zstride).
// epilogue (non-split only): +bias[n], *rowscale[m], relu; f32 or bf16 out.
// ---------------------------------------------------------------------------
template<int BM, int BN, int WM, int WN, bool GATHER>
__global__ void __launch_bounds__(256, 3)
gemm_bf16(const u16* __restrict__ A, int lda,
          const u16* __restrict__ Bt, int ldb,
          int N, int K, int KZ,
          const int* __restrict__ idx,
          float* __restrict__ Cf, u16* __restrict__ Cb, long zstride,
          const float* __restrict__ bias,
          const float* __restrict__ rowscale,
          int relu)
{
  constexpr int AISS = BM / 32;
  constexpr int BISS = BN / 32;
  constexpr int AF = WM / 16;
  constexpr int BF = WN / 16;
  constexpr int WGN = BN / WN;
  __shared__ __align__(16) u16 ldsA[BM * 64];
  __shared__ __align__(16) u16 ldsB[BN * 64];
  const int t = threadIdx.x;
  const int lane = t & 63;
  const int w = t >> 6;
  const int m0 = blockIdx.x * BM;
  const int n0 = blockIdx.y * BN;
  const int kOff = blockIdx.z * KZ;
  const int Kloc = min(KZ, K - kOff);
  const int wm = w / WGN, wn = w % WGN;
  const int sr = t >> 3;          // staging row within 32-row group
  const int sk = (t & 7) * 8;     // staging k col (elements)

  if (zstride) Cf += (long)blockIdx.z * zstride;

  const u16* arow[AISS];
#pragma unroll
  for (int j = 0; j < AISS; ++j) {
    int r = m0 + j * 32 + sr;
    long rr = GATHER ? (long)idx[r] : (long)r;
    arow[j] = A + rr * (long)lda + sk + kOff;
  }
  const u16* brow[BISS];
#pragma unroll
  for (int j = 0; j < BISS; ++j)
    brow[j] = Bt + (long)(n0 + j * 32 + sr) * ldb + sk + kOff;

  f32x4 acc[AF][BF];
#pragma unroll
  for (int i = 0; i < AF; ++i)
#pragma unroll
    for (int j = 0; j < BF; ++j)
      acc[i][j] = (f32x4){0.f, 0.f, 0.f, 0.f};

  for (int k0 = 0; k0 < Kloc; k0 += 64) {
#pragma unroll
    for (int j = 0; j < AISS; ++j)
      gld_lds16(arow[j] + k0, &ldsA[(j * 32 + w * 8) * 64]);
#pragma unroll
    for (int j = 0; j < BISS; ++j)
      gld_lds16(brow[j] + k0, &ldsB[(j * 32 + w * 8) * 64]);
    __syncthreads();
#pragma unroll
    for (int k2 = 0; k2 < 64; k2 += 32) {
      bf16x8 af[AF], bfv[BF];
#pragma unroll
      for (int i = 0; i < AF; ++i)
        af[i] = *(const bf16x8*)&ldsA[(wm * WM + i * 16 + (lane & 15)) * 64 + k2 + (lane >> 4) * 8];
#pragma unroll
      for (int i = 0; i < BF; ++i)
        bfv[i] = *(const bf16x8*)&ldsB[(wn * WN + i * 16 + (lane & 15)) * 64 + k2 + (lane >> 4) * 8];
#pragma unroll
      for (int i = 0; i < AF; ++i)
#pragma unroll
        for (int j = 0; j < BF; ++j)
          acc[i][j] = __builtin_amdgcn_mfma_f32_16x16x32_bf16(af[i], bfv[j], acc[i][j], 0, 0, 0);
    }
    __syncthreads();
  }

  const int er = (lane >> 4) * 4;
  const int ecn = lane & 15;
#pragma unroll
  for (int i = 0; i < AF; ++i)
#pragma unroll
    for (int j = 0; j < BF; ++j)
#pragma unroll
      for (int r = 0; r < 4; ++r) {
        long gm = m0 + wm * WM + i * 16 + er + r;
        long gn = n0 + wn * WN + j * 16 + ecn;
        float v = acc[i][j][r];
        if (bias) v += bias[gn];
        if (rowscale) v *= rowscale[gm];
        if (relu) v = fmaxf(v, 0.f);
        if (Cb) Cb[gm * N + gn] = f2b(v);
        else    Cf[gm * N + gn] = v;
      }
}

// ---------------------------------------------------------------------------
// fp32-A GEMM (affinity rows, gathered): C[m,n] = sum_k A[idx(m),k]*Bt[n,k]
// split-K partials. BM=64, BN=256, A converted fp32->bf16 in-register.
// ---------------------------------------------------------------------------
__global__ void __launch_bounds__(256, 3)
gemm_a32g(const float* __restrict__ A, int lda,
          const u16* __restrict__ Bt, int ldb,
          int N, int KZ,
          const int* __restrict__ idx,
          float* __restrict__ Cf, long zstride)
{
  constexpr int AF = 2, BF = 8, WGN = 2;  // BM=64 (WM=32), BN=256 (WN=128)
  __shared__ __align__(16) u16 ldsA[64 * 72];
  __shared__ __align__(16) u16 ldsB[256 * 64];
  const int t = threadIdx.x;
  const int lane = t & 63;
  const int w = t >> 6;
  const int m0 = blockIdx.x * 64;
  const int n0 = blockIdx.y * 256;
  const int kOff = blockIdx.z * KZ;
  const int wm = w / WGN, wn = w % WGN;
  const int sr = t >> 3;
  const int sk = (t & 7) * 8;

  Cf += (long)blockIdx.z * zstride;

  const u16* brow[8];
#pragma unroll
  for (int j = 0; j < 8; ++j)
    brow[j] = Bt + (long)(n0 + j * 32 + sr) * ldb + sk + kOff;

  int r = m0 + (t >> 2);
  long rowsel = idx ? (long)idx[r] : (long)r;
  const float* ar_direct = A + rowsel * (long)lda + (t & 3) * 16 + kOff;

  f32x4 acc[AF][BF];
#pragma unroll
  for (int i = 0; i < AF; ++i)
#pragma unroll
    for (int j = 0; j < BF; ++j)
      acc[i][j] = (f32x4){0.f, 0.f, 0.f, 0.f};

  for (int k0 = 0; k0 < KZ; k0 += 64) {
#pragma unroll
    for (int j = 0; j < 8; ++j)
      gld_lds16(brow[j] + k0, &ldsB[(j * 32 + w * 8) * 64]);

    const float4* src = (const float4*)(ar_direct + k0);
    float4 v0 = src[0], v1 = src[1], v2 = src[2], v3 = src[3];
    u16x8 ua, ub;
    ua[0] = f2b(v0.x); ua[1] = f2b(v0.y); ua[2] = f2b(v0.z); ua[3] = f2b(v0.w);
    ua[4] = f2b(v1.x); ua[5] = f2b(v1.y); ua[6] = f2b(v1.z); ua[7] = f2b(v1.w);
    ub[0] = f2b(v2.x); ub[1] = f2b(v2.y); ub[2] = f2b(v2.z); ub[3] = f2b(v2.w);
    ub[4] = f2b(v3.x); ub[5] = f2b(v3.y); ub[6] = f2b(v3.z); ub[7] = f2b(v3.w);
    int ro = (t >> 2) * 72 + (t & 3) * 16;
    *(u16x8*)&ldsA[ro] = ua;
    *(u16x8*)&ldsA[ro + 8] = ub;
    __syncthreads();
#pragma unroll
    for (int k2 = 0; k2 < 64; k2 += 32) {
      bf16x8 af[AF], bfv[BF];
#pragma unroll
      for (int i = 0; i < AF; ++i)
        af[i] = *(const bf16x8*)&ldsA[(wm * 32 + i * 16 + (lane & 15)) * 72 + k2 + (lane >> 4) * 8];
#pragma unroll
      for (int i = 0; i < BF; ++i)
        bfv[i] = *(const bf16x8*)&ldsB[(wn * 128 + i * 16 + (lane & 15)) * 64 + k2 + (lane >> 4) * 8];
#pragma unroll
      for (int i = 0; i < AF; ++i)
#pragma unroll
        for (int j = 0; j < BF; ++j)
          acc[i][j] = __builtin_amdgcn_mfma_f32_16x16x32_bf16(af[i], bfv[j], acc[i][j], 0, 0, 0);
    }
    __syncthreads();
  }

  const int er = (lane >> 4) * 4;
  const int ecn = lane & 15;
#pragma unroll
  for (int i = 0; i < AF; ++i)
#pragma unroll
    for (int j = 0; j < BF; ++j)
#pragma unroll
      for (int rr2 = 0; rr2 < 4; ++rr2) {
        long gm = m0 + wm * 32 + i * 16 + er + rr2;
        long gn = n0 + wn * 128 + j * 16 + ecn;
        Cf[gm * N + gn] = acc[i][j][rr2];
      }
}

// sum `parts` partial buffers of n floats, optional +bias[col], col = i&nmask
__global__ void reduceP(const float* __restrict__ p, long n, int parts,
                        int nmask, const float* __restrict__ bias,
                        float* __restrict__ out) {
  long i = ((long)blockIdx.x * 256 + threadIdx.x) * 4;
  if (i >= n) return;
  float4 a = *(const float4*)&p[i];
  for (int z = 1; z < parts; ++z) {
    float4 b = *(const float4*)&p[(long)z * n + i];
    a.x += b.x; a.y += b.y; a.z += b.z; a.w += b.w;
  }
  if (bias) {
    int c = (int)(i & nmask);
    a.x += bias[c]; a.y += bias[c + 1]; a.z += bias[c + 2]; a.w += bias[c + 3];
  }
  *(float4*)&out[i] = a;
}

// ---------------------------------------------------------------------------
// transpose-convert: affinity fp32 [8192 x 8192] -> affT bf16 [8192 x 8192]
// affT[c][r] = bf16(A[r][c]).  64x64 tiles via LDS.
// ---------------------------------------------------------------------------
__global__ void __launch_bounds__(256)
transcvt(const float* __restrict__ in, u16* __restrict__ out) {
  __shared__ float tile[64][65];
  const int t = threadIdx.x;
  const int r0 = blockIdx.x * 64, c0 = blockIdx.y * 64;
  {
    int rr = t >> 2, cb = (t & 3) * 16;
    const float4* src = (const float4*)&in[(long)(r0 + rr) * 8192 + c0 + cb];
    float4 a = src[0], b = src[1], c = src[2], d = src[3];
    float* dst = &tile[rr][cb];
    *(float4*)(dst) = a; *(float4*)(dst + 4) = b;
    *(float4*)(dst + 8) = c; *(float4*)(dst + 12) = d;
  }
  __syncthreads();
  {
    int cc = t >> 2, rb = (t & 3) * 16;
    u16x8 ua, ub;
#pragma unroll
    for (int j = 0; j < 8; ++j) {
      ua[j] = f2b(tile[rb + j][cc]);
      ub[j] = f2b(tile[rb + 8 + j][cc]);
    }
    u16* dst = &out[(long)(c0 + cc) * 8192 + r0 + rb];
    *(u16x8*)dst = ua;
    *(u16x8*)(dst + 8) = ub;
  }
}

// ---------------------------------------------------------------------------
// split-precision GEMM: C[M,N] = relu(A_f32[M,K] @ Bt[N,K]^T + bias), fp32 out
// A staged as hi+lo bf16 (a = hi + lo), 2x MFMA -> ~19-bit effective mantissa.
// ---------------------------------------------------------------------------
__global__ void __launch_bounds__(256, 2)
gemm_sp(const float* __restrict__ A, int lda,
        const u16* __restrict__ Bt, int ldb,
        int N, int K,
        const float* __restrict__ bias,
        float* __restrict__ Cf)
{
  __shared__ __align__(16) u16 ldsAh[64 * 64];
  __shared__ __align__(16) u16 ldsAl[64 * 64];
  __shared__ __align__(16) u16 ldsB[64 * 64];
  const int t = threadIdx.x, lane = t & 63, w = t >> 6;
  const int m0 = blockIdx.x * 64, n0 = blockIdx.y * 64;
  const int wm = w >> 1, wn = w & 1;
  const int sr = t >> 3, sk = (t & 7) * 8;
  const int ar = t >> 2;          // 0..63 tile row
  const int ak = (t & 3) * 16;    // k offset: 0,16,32,48
  const float* Ap = A + (long)(m0 + ar) * lda + ak;
  const u16* brow[2];
#pragma unroll
  for (int j = 0; j < 2; ++j)
    brow[j] = Bt + (long)(n0 + j * 32 + sr) * ldb + sk;

  f32x4 acc[2][2];
#pragma unroll
  for (int i = 0; i < 2; ++i)
#pragma unroll
    for (int j = 0; j < 2; ++j)
      acc[i][j] = (f32x4){0.f, 0.f, 0.f, 0.f};

  for (int k0 = 0; k0 < K; k0 += 64) {
#pragma unroll
    for (int j = 0; j < 2; ++j)
      gld_lds16(brow[j] + k0, &ldsB[(j * 32 + w * 8) * 64]);
    const float4* src = (const float4*)(Ap + k0);
    float4 v0 = src[0], v1 = src[1], v2 = src[2], v3 = src[3];
    float f[16] = {v0.x, v0.y, v0.z, v0.w, v1.x, v1.y, v1.z, v1.w,
                   v2.x, v2.y, v2.z, v2.w, v3.x, v3.y, v3.z, v3.w};
    u16x8 h0, h1v, l0, l1v;
#pragma unroll
    for (int i = 0; i < 8; ++i) {
      u16 h = f2b(f[i]);       h0[i] = h;  l0[i] = f2b(f[i] - b2f(h));
      u16 g = f2b(f[8 + i]);   h1v[i] = g; l1v[i] = f2b(f[8 + i] - b2f(g));
    }
    *(u16x8*)&ldsAh[ar * 64 + ak] = h0;
    *(u16x8*)&ldsAh[ar * 64 + ak + 8] = h1v;
    *(u16x8*)&ldsAl[ar * 64 + ak] = l0;
    *(u16x8*)&ldsAl[ar * 64 + ak + 8] = l1v;
    __syncthreads();
#pragma unroll
    for (int k2 = 0; k2 < 64; k2 += 32) {
      bf16x8 ah[2], al[2], bv[2];
#pragma unroll
      for (int i = 0; i < 2; ++i) {
        int off = (wm * 32 + i * 16 + (lane & 15)) * 64 + k2 + (lane >> 4) * 8;
        ah[i] = *(const bf16x8*)&ldsAh[off];
        al[i] = *(const bf16x8*)&ldsAl[off];
      }
#pragma unroll
      for (int i = 0; i < 2; ++i)
        bv[i] = *(const bf16x8*)&ldsB[(wn * 32 + i * 16 + (lane & 15)) * 64 + k2 + (lane >> 4) * 8];
#pragma unroll
      for (int i = 0; i < 2; ++i)
#pragma unroll
        for (int j = 0; j < 2; ++j) {
          acc[i][j] = __builtin_amdgcn_mfma_f32_16x16x32_bf16(ah[i], bv[j], acc[i][j], 0, 0, 0);
          acc[i][j] = __builtin_amdgcn_mfma_f32_16x16x32_bf16(al[i], bv[j], acc[i][j], 0, 0, 0);
        }
    }
    __syncthreads();
  }

  const int er = (lane >> 4) * 4;
  const int ecn = lane & 15;
#pragma unroll
  for (int i = 0; i < 2; ++i)
#pragma unroll
    for (int j = 0; j < 2; ++j)
#pragma unroll
      for (int r = 0; r < 4; ++r) {
        long gm = m0 + wm * 32 + i * 16 + er + r;
        long gn = n0 + wn * 32 + j * 16 + ecn;
        float v = acc[i][j][r] + bias[gn];
        Cf[gm * N + gn] = fmaxf(v, 0.f);
      }
}

// ---------------------------------------------------------------------------
// small kernels
// ---------------------------------------------------------------------------
__global__ void cvt_bf16(const float* __restrict__ x, u16* __restrict__ y, long n) {
  long i = ((long)blockIdx.x * 256 + threadIdx.x) * 4;
  if (i < n) {
    float4 v = *(const float4*)&x[i];
    u16 a = f2b(v.x), b = f2b(v.y), c = f2b(v.z), d = f2b(v.w);
    u32 lo = (u32)a | ((u32)b << 16);
    u32 hi = (u32)c | ((u32)d << 16);
    *(uint2*)&y[i] = make_uint2(lo, hi);
  }
}

// in [R x C] f32 -> out [C x Rpad] bf16 (transpose + convert, zero-pad rows >= R)
__global__ void wtrans(const float* __restrict__ in, u16* __restrict__ out,
                       int R, int C, int Rpad) {
  __shared__ float tile[32][33];
  int r0 = blockIdx.x * 32, c0 = blockIdx.y * 32;
  int tx = threadIdx.x & 31, ty = threadIdx.x >> 5;  // 32 x 8
  for (int j = 0; j < 32; j += 8) {
    int r = r0 + ty + j, c = c0 + tx;
    tile[ty + j][tx] = (r < R && c < C) ? in[(long)r * C + c] : 0.f;
  }
  __syncthreads();
  for (int j = 0; j < 32; j += 8) {
    int c = c0 + ty + j, r = r0 + tx;
    if (c < C && r < Rpad) out[(long)c * Rpad + r] = f2b(tile[tx][ty + j]);
  }
}

// bf16 transpose: in [R x C] -> out [C x R]
__global__ void btrans(const u16* __restrict__ in, u16* __restrict__ out, int R, int C) {
  __shared__ u16 tile[32][34];
  int r0 = blockIdx.x * 32, c0 = blockIdx.y * 32;
  int tx = threadIdx.x & 31, ty = threadIdx.x >> 5;
  for (int j = 0; j < 32; j += 8)
    tile[ty + j][tx] = in[(long)(r0 + ty + j) * C + c0 + tx];
  __syncthreads();
  for (int j = 0; j < 32; j += 8)
    out[(long)(c0 + ty + j) * R + r0 + tx] = tile[tx][ty + j];
}

// both graphs in one launch: blockIdx.y selects graph
__global__ void edge_deg2(const int* __restrict__ ei_a, const float* __restrict__ ew_a,
                          const int* __restrict__ ei_b, const float* __restrict__ ew_b,
                          int E, float* degw_a, int* cnt_a,
                          float* degw_b, int* cnt_b) {
  int e = blockIdx.x * 256 + threadIdx.x;
  if (e >= E) return;
  const int* ei = blockIdx.y ? ei_b : ei_a;
  const float* ew = blockIdx.y ? ew_b : ew_a;
  float* degw = blockIdx.y ? degw_b : degw_a;
  int* cnt = blockIdx.y ? cnt_b : cnt_a;
  int dst = ei[E + e];
  atomicAdd(&degw[dst], ew[e]);
  atomicAdd(&cnt[dst], 1);
}

// 2 blocks: block b scans cnt -> rowptr/cursor and computes dinv for graph b
__global__ void scan_dinv(const int* __restrict__ cnt_a, int* rowptr_a, int* cursor_a,
                          const float* __restrict__ degw_a, float* dinv_a,
                          const int* __restrict__ cnt_b, int* rowptr_b, int* cursor_b,
                          const float* __restrict__ degw_b, float* dinv_b) {
  const int* cnt = blockIdx.x ? cnt_b : cnt_a;
  int* rowptr = blockIdx.x ? rowptr_b : rowptr_a;
  int* cursor = blockIdx.x ? cursor_b : cursor_a;
  const float* degw = blockIdx.x ? degw_b : degw_a;
  float* dinv = blockIdx.x ? dinv_b : dinv_a;
  __shared__ int lds[256];
  int t = threadIdx.x;
  int c0 = t * 32;
  int loc[32];
  int s = 0;
#pragma unroll
  for (int i = 0; i < 32; ++i) { loc[i] = cnt[c0 + i]; s += loc[i]; }
  lds[t] = s;
  __syncthreads();
  for (int off = 1; off < 256; off <<= 1) {
    int add = (t >= off) ? lds[t - off] : 0;
    __syncthreads();
    lds[t] += add;
    __syncthreads();
  }
  int run = lds[t] - s;
#pragma unroll
  for (int i = 0; i < 32; ++i) {
    rowptr[c0 + i] = run;
    cursor[c0 + i] = run;
    run += loc[i];
  }
  if (t == 255) rowptr[8192] = run;
#pragma unroll
  for (int i = 0; i < 32; ++i)
    dinv[c0 + i] = rsqrtf(degw[c0 + i] + 1.0f);
}

__global__ void edge_scatter2(const int* __restrict__ ei_a, const float* __restrict__ ew_a,
                              const int* __restrict__ ei_b, const float* __restrict__ ew_b,
                              int E, int* cursor_a, int2* edges_a,
                              int* cursor_b, int2* edges_b) {
  int e = blockIdx.x * 256 + threadIdx.x;
  if (e >= E) return;
  const int* ei = blockIdx.y ? ei_b : ei_a;
  const float* ew = blockIdx.y ? ew_b : ew_a;
  int* cursor = blockIdx.y ? cursor_b : cursor_a;
  int2* edges = blockIdx.y ? edges_b : edges_a;
  int src = ei[e], dst = ei[E + e];
  int pos = atomicAdd(&cursor[dst], 1);
  edges[pos] = make_int2(src, __float_as_int(ew[e]));
}

// out[i] = leaky( bias + dinv[i] * (hs[i] + sum_e w_e * hs[src_e]) )
__global__ void gcn_aggregate(const u16* __restrict__ hs,
                              const int* __restrict__ rowptr,
                              const int2* __restrict__ edges,
                              const float* __restrict__ dinv,
                              const float* __restrict__ bias,
                              u16* __restrict__ out) {
  const int i = blockIdx.x;
  const int t = threadIdx.x;  // 256, each owns cols 2t, 2t+1
  const u32* base = (const u32*)hs;
  u32 hv = base[i * 256 + t];
  float a0 = b2f((u16)(hv & 0xffff));
  float a1 = b2f((u16)(hv >> 16));
  int s = rowptr[i], e = rowptr[i + 1];
  int p = s;
  for (; p + 4 <= e; p += 4) {
    int2 e0 = edges[p], e1 = edges[p + 1], e2 = edges[p + 2], e3 = edges[p + 3];
    u32 v0 = base[(long)e0.x * 256 + t];
    u32 v1 = base[(long)e1.x * 256 + t];
    u32 v2 = base[(long)e2.x * 256 + t];
    u32 v3 = base[(long)e3.x * 256 + t];
    float w0 = __int_as_float(e0.y), w1 = __int_as_float(e1.y);
    float w2 = __int_as_float(e2.y), w3 = __int_as_float(e3.y);
    a0 += w0 * b2f((u16)(v0 & 0xffff)); a1 += w0 * b2f((u16)(v0 >> 16));
    a0 += w1 * b2f((u16)(v1 & 0xffff)); a1 += w1 * b2f((u16)(v1 >> 16));
    a0 += w2 * b2f((u16)(v2 & 0xffff)); a1 += w2 * b2f((u16)(v2 >> 16));
    a0 += w3 * b2f((u16)(v3 & 0xffff)); a1 += w3 * b2f((u16)(v3 >> 16));
  }
  for (; p < e; ++p) {
    int2 ee = edges[p];
    u32 v = base[(long)ee.x * 256 + t];
    float ww = __int_as_float(ee.y);
    a0 += ww * b2f((u16)(v & 0xffff));
    a1 += ww * b2f((u16)(v >> 16));
  }
  float di = dinv[i];
  float o0 = bias[2 * t] + di * a0;
  float o1 = bias[2 * t + 1] + di * a1;
  o0 = (o0 >= 0.f) ? o0 : 0.01f * o0;
  o1 = (o1 >= 0.f) ? o1 : 0.01f * o1;
  ((u32*)out)[i * 256 + t] = (u32)f2b(o0) | ((u32)f2b(o1) << 16);
}

// all feature-column sums in one kernel. grid (14, 32), 128 rows per y-block
__global__ void colsum_all(const float* __restrict__ d_vecs, const float* __restrict__ p_emb,
                           const u16* __restrict__ ec, const u16* __restrict__ gos,
                           const float* __restrict__ t1, const float* __restrict__ t2,
                           const int* __restrict__ didx, const int* __restrict__ pidx,
                           float* __restrict__ out) {
  int c = blockIdx.x * 256 + threadIdx.x;
  if (c >= 3372) return;
  int r0 = blockIdx.y * 128;
  float s = 0.f;
  if (c < 300) {
    for (int r = r0; r < r0 + 128; ++r) s += d_vecs[(long)r * 300 + c];
  } else if (c < 1324) {
    int cc = c - 300;
    for (int r = r0; r < r0 + 128; ++r) s += p_emb[(long)r * 1024 + cc];
  } else if (c < 1836) {
    int cc = c - 1324;
    for (int r = r0; r < r0 + 128; ++r) s += b2f(ec[(long)didx[r] * 512 + cc]);
  } else if (c < 2348) {
    int cc = c - 1836;
    for (int r = r0; r < r0 + 128; ++r) s += t1[(long)r * 512 + cc];
  } else if (c < 2860) {
    int cc = c - 2348;
    for (int r = r0; r < r0 + 128; ++r) s += b2f(gos[(long)pidx[r] * 512 + cc]);
  } else {
    int cc = c - 2860;
    for (int r = r0; r < r0 + 128; ++r) s += t2[(long)r * 512 + cc];
  }
  atomicAdd(&out[c], s);
}

// feature assembly (column-centered): [B x 3392] bf16
__global__ void assemble(const float* __restrict__ d_vecs, const float* __restrict__ p_emb,
                         const u16* __restrict__ ec, const u16* __restrict__ gos,
                         const float* __restrict__ t1, const float* __restrict__ t2,
                         const int* __restrict__ didx, const int* __restrict__ pidx,
                         const float* __restrict__ cs, u16* __restrict__ feat) {
  const float is = 1.f / 4096.f;
  int b = blockIdx.x;
  int t = threadIdx.x;
  long ob = (long)b * KPAD;
  int di = didx[b], pi = pidx[b];
  for (int j = t; j < 300; j += 256)
    feat[ob + j] = f2b(d_vecs[(long)b * 300 + j] - cs[j] * is);
  for (int j = t; j < 1024; j += 256)
    feat[ob + 300 + j] = f2b(p_emb[(long)b * 1024 + j] - cs[300 + j] * is);
  for (int j = t; j < 512; j += 256) {
    feat[ob + 1324 + j] = f2b(b2f(ec[(long)di * 512 + j]) - cs[1324 + j] * is);
    feat[ob + 1836 + j] = f2b(t1[(long)b * 512 + j] - cs[1836 + j] * is);
    feat[ob + 2348 + j] = f2b(b2f(gos[(long)pi * 512 + j]) - cs[2348 + j] * is);
    feat[ob + 2860 + j] = f2b(t2[(long)b * 512 + j] - cs[2860 + j] * is);
  }
  for (int j = t; j < 20; j += 256) feat[ob + 3372 + j] = 0;
}

// 32 rows per block
__global__ void bn_stats(const float* __restrict__ x, int N,
                         float* __restrict__ sum, float* __restrict__ sumsq) {
  int r0 = blockIdx.x * 32;
  int t = threadIdx.x;
  for (int c = t; c < N; c += 256) {
    float s = 0.f, q = 0.f;
    for (int r = 0; r < 32; ++r) {
      float v = x[(long)(r0 + r) * N + c];
      s += v; q += v * v;
    }
    atomicAdd(&sum[c], s);
    atomicAdd(&sumsq[c], q);
  }
}

__global__ void bn_apply(const float* __restrict__ x, int M, int N, int nmask,
                         const float* __restrict__ sum, const float* __restrict__ sumsq,
                         const float* __restrict__ g, const float* __restrict__ be,
                         u16* __restrict__ y) {
  long i = (long)blockIdx.x * 256 + threadIdx.x;
  if (i >= (long)M * N) return;
  int c = (int)(i & nmask);
  float m = sum[c] / (float)M;
  float v = sumsq[c] / (float)M - m * m;
  float sc = g[c] * rsqrtf(v + 1e-5f);
  float sh = be[c] - m * sc;
  float o = fmaxf(x[i] * sc + sh, 0.f);
  y[i] = f2b(o);
}

// y[b] = sum_j h[b,j] * w[j] + b0 ; one wave per row, N=256
__global__ void final_dot(const u16* __restrict__ h, const float* __restrict__ w,
                          const float* __restrict__ b0, float* __restrict__ y) {
  int wv = threadIdx.x >> 6, lane = threadIdx.x & 63;
  int row = blockIdx.x * 4 + wv;
  const u16* hr = h + (long)row * 256;
  ushort4 u = *(const ushort4*)&hr[lane * 4];
  float acc = b2f(u.x) * w[lane * 4] + b2f(u.y) * w[lane * 4 + 1] +
              b2f(u.z) * w[lane * 4 + 2] + b2f(u.w) * w[lane * 4 + 3];
  for (int off = 32; off; off >>= 1) acc += __shfl_down(acc, off);
  if (lane == 0) y[row] = acc + b0[0];
}

// ---------------------------------------------------------------------------
extern "C" void kernel_launch(void* const* d_in, const int* in_sizes, int n_in,
                              void* d_out, int out_size, void* d_ws, size_t ws_size,
                              hipStream_t stream) {
  (void)in_sizes; (void)n_in; (void)out_size; (void)ws_size;
  const int*   d_index  = (const int*)d_in[0];
  const int*   p_index  = (const int*)d_in[1];
  const float* d_vecs   = (const float*)d_in[2];
  const float* p_emb    = (const float*)d_in[3];
  const float* d_ecfps  = (const float*)d_in[4];
  const int*   d_ei     = (const int*)d_in[5];
  const float* d_ew     = (const float*)d_in[6];
  const float* p_gos    = (const float*)d_in[7];
  const int*   p_ei     = (const int*)d_in[8];
  const float* p_ew     = (const float*)d_in[9];
  const float* affinity = (const float*)d_in[10];
  const float* W_e  = (const float*)d_in[11];
  const float* b_e  = (const float*)d_in[12];
  const float* W_g  = (const float*)d_in[13];
  const float* b_g  = (const float*)d_in[14];
  const float* W1   = (const float*)d_in[15];
  const float* b1   = (const float*)d_in[16];
  const float* W2   = (const float*)d_in[17];
  const float* b2   = (const float*)d_in[18];
  const float* Wo1  = (const float*)d_in[19];
  const float* bo1  = (const float*)d_in[20];
  const float* g1   = (const float*)d_in[21];
  const float* be1  = (const float*)d_in[22];
  const float* Wo2  = (const float*)d_in[23];
  const float* bo2  = (const float*)d_in[24];
  const float* g2   = (const float*)d_in[25];
  const float* be2  = (const float*)d_in[26];
  const float* Wo3  = (const float*)d_in[27];
  const float* bo3  = (const float*)d_in[28];
  float* y_out = (float*)d_out;

  char* p = (char*)d_ws;
  auto alloc = [&](size_t bytes) -> char* {
    char* q = p;
    p += (bytes + 255) & ~(size_t)255;
    return q;
  };

  // zero-init block (one memset)
  char* zero_start = p;
  float* degw_e = (float*)alloc(NDN * 4);
  int*   cnt_e  = (int*)alloc(NDN * 4);
  float* degw_p = (float*)alloc(NPN * 4);
  int*   cnt_p  = (int*)alloc(NPN * 4);
  float* bnsum1 = (float*)alloc(1024 * 4);
  float* bnsq1  = (float*)alloc(1024 * 4);
  float* bnsum2 = (float*)alloc(256 * 4);
  float* bnsq2  = (float*)alloc(256 * 4);
  float* colsum = (float*)alloc(KPAD * 4);
  size_t zero_bytes = (size_t)(p - zero_start);

  float* dinv_e   = (float*)alloc(NDN * 4);
  float* dinv_p   = (float*)alloc(NPN * 4);
  int*   rowptr_e = (int*)alloc((NDN + 1) * 4);
  int*   cursor_e = (int*)alloc(NDN * 4);
  int*   rowptr_p = (int*)alloc((NPN + 1) * 4);
  int*   cursor_p = (int*)alloc(NPN * 4);
  int2*  edges_e  = (int2*)alloc((size_t)EDN * 8);
  int2*  edges_p  = (int2*)alloc((size_t)EPN * 8);
  u16* x_e_b  = (u16*)alloc((size_t)NDN * 1024 * 2);   // aliased: tmp1_f after G1
  u16* x_g_b  = (u16*)alloc((size_t)NPN * 1024 * 2);   // aliased: tmp2_f after G2
  u16* WeT    = (u16*)alloc((size_t)512 * 1024 * 2);
  u16* WgT    = (u16*)alloc((size_t)512 * 1024 * 2);
  u16* W1T    = (u16*)alloc((size_t)512 * 512 * 2);
  u16* W2T    = (u16*)alloc((size_t)512 * 512 * 2);
  u16* Wo1T   = (u16*)alloc((size_t)1024 * KPAD * 2);
  u16* Wo2T   = (u16*)alloc((size_t)256 * 1024 * 2);
  u16* hs_e   = (u16*)alloc((size_t)NDN * 512 * 2);    // aliased: t1_f after aggregate
  u16* hs_g   = (u16*)alloc((size_t)NPN * 512 * 2);    // aliased: t2_f after aggregate
  u16* ec_b   = (u16*)alloc((size_t)NDN * 512 * 2);
  u16* gos_b  = (u16*)alloc((size_t)NPN * 512 * 2);
  u16* ecT_b  = (u16*)alloc((size_t)512 * NDN * 2);
  u16* gosT_b = (u16*)alloc((size_t)512 * NPN * 2);
  u16* affT_b = (u16*)alloc((size_t)8192 * 8192 * 2);  // 128 MB
  u16* feat_b = (u16*)alloc((size_t)BBN * KPAD * 2);
  float* h1   = (float*)alloc((size_t)BBN * 1024 * 4);
  u16* h1n_b  = (u16*)alloc((size_t)BBN * 1024 * 2);
  float* h2   = (float*)alloc((size_t)BBN * 256 * 4);
  u16* h2n_b  = (u16*)alloc((size_t)BBN * 256 * 2);
  // split-K partials: max over uses = G3 4x(4096x512) = G7 2x(4096x1024) = 33.6MB
  float* partK = (float*)alloc((size_t)4 * BBN * 512 * 4);

  // aliases (exact-size overlays; source buffers dead before first write)
  float* tmp1_f = (float*)x_e_b;   // [4096 x 512] f32 (b-indexed)
  float* tmp2_f = (float*)x_g_b;   // [4096 x 512] f32 (b-indexed)
  float* t1_f   = (float*)hs_e;    // [4096 x 512] f32
  float* t2_f   = (float*)hs_g;

  hipMemsetAsync(zero_start, 0, zero_bytes, stream);

  // input conversions
  cvt_bf16<<<8192, 256, 0, stream>>>(d_ecfps, x_e_b, (long)NDN * 1024);
  cvt_bf16<<<8192, 256, 0, stream>>>(p_gos, x_g_b, (long)NPN * 1024);
  wtrans<<<dim3(32, 16), 256, 0, stream>>>(W_e, WeT, 1024, 512, 1024);
  wtrans<<<dim3(32, 16), 256, 0, stream>>>(W_g, WgT, 1024, 512, 1024);
  wtrans<<<dim3(16, 16), 256, 0, stream>>>(W1, W1T, 512, 512, 512);
  wtrans<<<dim3(16, 16), 256, 0, stream>>>(W2, W2T, 512, 512, 512);
  wtrans<<<dim3(106, 32), 256, 0, stream>>>(Wo1, Wo1T, 3372, 1024, KPAD);
  wtrans<<<dim3(32, 8), 256, 0, stream>>>(Wo2, Wo2T, 1024, 256, 1024);

  // affinity^T bf16 (for G4)
  transcvt<<<dim3(128, 128), 256, 0, stream>>>(affinity, affT_b);

  // graph prep
  edge_deg2<<<dim3(EDN / 256, 2), 256, 0, stream>>>(d_ei, d_ew, p_ei, p_ew, EDN,
                                                    degw_e, cnt_e, degw_p, cnt_p);
  scan_dinv<<<2, 256, 0, stream>>>(cnt_e, rowptr_e, cursor_e, degw_e, dinv_e,
                                   cnt_p, rowptr_p, cursor_p, degw_p, dinv_p);
  edge_scatter2<<<dim3(EDN / 256, 2), 256, 0, stream>>>(d_ei, d_ew, p_ei, p_ew, EDN,
                                                        cursor_e, edges_e,
                                                        cursor_p, edges_p);

  // G1/G2: hs = dinv[m] * (x @ W)   [8192 x 512] bf16
  gemm_bf16<64, 128, 32, 64, false><<<dim3(128, 4), 256, 0, stream>>>(
      x_e_b, 1024, WeT, 1024, 512, 1024, 1024, nullptr,
      (float*)nullptr, hs_e, 0, (const float*)nullptr, dinv_e, 0);
  gemm_bf16<64, 128, 32, 64, false><<<dim3(128, 4), 256, 0, stream>>>(
      x_g_b, 1024, WgT, 1024, 512, 1024, 1024, nullptr,
      (float*)nullptr, hs_g, 0, (const float*)nullptr, dinv_p, 0);

  // aggregation -> node features (bf16)
  gcn_aggregate<<<NDN, 256, 0, stream>>>(hs_e, rowptr_e, edges_e, dinv_e, b_e, ec_b);
  gcn_aggregate<<<NPN, 256, 0, stream>>>(hs_g, rowptr_p, edges_p, dinv_p, b_g, gos_b);

  // transposes for K-contiguous B operands
  btrans<<<dim3(256, 16), 256, 0, stream>>>(ec_b, ecT_b, NDN, 512);
  btrans<<<dim3(256, 16), 256, 0, stream>>>(gos_b, gosT_b, NPN, 512);

  // G3: tmp1 = affinity[d_index] @ gos  [4096 x 512] fp32, split-K=4
  gemm_a32g<<<dim3(64, 2, 4), 256, 0, stream>>>(
      affinity, 8192, gosT_b, 8192, 512, 2048, d_index, partK, (long)BBN * 512);
  reduceP<<<2048, 256, 0, stream>>>(partK, (long)BBN * 512, 4, 0, nullptr, tmp1_f);

  // G4: tmp2 = (affinity^T)[p_index] @ ecfps  [4096 x 512] fp32, split-K=2
  gemm_bf16<64, 128, 32, 64, true><<<dim3(64, 4, 2), 256, 0, stream>>>(
      affT_b, 8192, ecT_b, 8192, 512, 8192, 4096, p_index,
      partK, (u16*)nullptr, (long)BBN * 512,
      (const float*)nullptr, (const float*)nullptr, 0);
  reduceP<<<2048, 256, 0, stream>>>(partK, (long)BBN * 512, 2, 0, nullptr, tmp2_f);

  // G5/G6: split-precision: t = relu(tmp @ W + b) fp32
  gemm_sp<<<dim3(64, 8), 256, 0, stream>>>(
      tmp1_f, 512, W1T, 512, 512, 512, b1, t1_f);
  gemm_sp<<<dim3(64, 8), 256, 0, stream>>>(
      tmp2_f, 512, W2T, 512, 512, 512, b2, t2_f);

  // feature column sums (centering; exactly BN1-equivalent)
  colsum_all<<<dim3(14, 32), 256, 0, stream>>>(d_vecs, p_emb, ec_b, gos_b,
                                               t1_f, t2_f, d_index, p_index, colsum);

  assemble<<<BBN, 256, 0, stream>>>(d_vecs, p_emb, ec_b, gos_b, t1_f, t2_f,
                                    d_index, p_index, colsum, feat_b);

  // G7: h1 = feat_c @ Wo1 + bo1  (fp32, split-K=2, bias in reduce)
  gemm_bf16<64, 128, 32, 64, false><<<dim3(64, 8, 2), 256, 0, stream>>>(
      feat_b, KPAD, Wo1T, KPAD, 1024, KPAD, 1728, nullptr,
      partK, (u16*)nullptr, (long)BBN * 1024,
      (const float*)nullptr, (const float*)nullptr, 0);
  reduceP<<<4096, 256, 0, stream>>>(partK, (long)BBN * 1024, 2, 1023, bo1, h1);
  bn_stats<<<128, 256, 0, stream>>>(h1, 1024, bnsum1, bnsq1);
  bn_apply<<<16384, 256, 0, stream>>>(h1, BBN, 1024, 1023, bnsum1, bnsq1, g1, be1, h1n_b);

  // G8: h2 = h1n @ Wo2 + bo2 (fp32 out)
  gemm_bf16<64, 64, 32, 32, false><<<dim3(64, 4), 256, 0, stream>>>(
      h1n_b, 1024, Wo2T, 1024, 256, 1024, 1024, nullptr,
      h2, (u16*)nullptr, 0, bo2, (const float*)nullptr, 0);
  bn_stats<<<128, 256, 0, stream>>>(h2, 256, bnsum2, bnsq2);
  bn_apply<<<4096, 256, 0, stream>>>(h2, BBN, 256, 255, bnsum2, bnsq2, g2, be2, h2n_b);

  final_dot<<<1024, 256, 0, stream>>>(h2n_b, Wo3, bo3, y_out);
}

// Round 5
// 1046.017 us; speedup vs baseline: 1.4062x; 1.0734x over previous
//
#include <hip/hip_runtime.h>
#include <stdint.h>
#include <stddef.h>

typedef unsigned short u16;
typedef unsigned int u32;
typedef __attribute__((ext_vector_type(8))) short bf16x8;
typedef __attribute__((ext_vector_type(8))) u16 u16x8;
typedef __attribute__((ext_vector_type(4))) float f32x4;

#define NDN 8192
#define NPN 8192
#define EDN 262144
#define EPN 262144
#define BBN 4096
#define KPAD 3392   // 3372 padded to multiple of 64

__device__ __forceinline__ u16 f2b(float f) {
  u32 u = __float_as_uint(f);
  u32 r = (u + 0x7fffu + ((u >> 16) & 1u)) >> 16;  // RTNE
  return (u16)r;
}
__device__ __forceinline__ float b2f(u16 h) {
  return __uint_as_float(((u32)h) << 16);
}

__device__ __forceinline__ void gld_lds16(const void* g, void* l) {
  __builtin_amdgcn_global_load_lds(
      (const __attribute__((address_space(1))) u32*)g,
      (__attribute__((address_space(3))) u32*)l, 16, 0, 0);
}

// ---------------------------------------------------------------------------
// bf16 GEMM: C[M,N] = gather(A)[M,K] @ Bt[N,K]^T  (both K-contiguous bf16)
// split-K via gridDim.z (KZ = per-split len, partial z at Cf + z*zstride).
// epilogue (non-split only): +bias[n], *rowscale[m], relu; f32 or bf16 out.
// ---------------------------------------------------------------------------
template<int BM, int BN, int WM, int WN, bool GATHER>
__global__ void __launch_bounds__(256, 3)
gemm_bf16(const u16* __restrict__ A, int lda,
          const u16* __restrict__ Bt, int ldb,
          int N, int K, int KZ,
          const int* __restrict__ idx,
          float* __restrict__ Cf, u16* __restrict__ Cb, long zstride,
          const float* __restrict__ bias,
          const float* __restrict__ rowscale,
          int relu)
{
  constexpr int AISS = BM / 32;
  constexpr int BISS = BN / 32;
  constexpr int AF = WM / 16;
  constexpr int BF = WN / 16;
  constexpr int WGN = BN / WN;
  __shared__ __align__(16) u16 ldsA[BM * 64];
  __shared__ __align__(16) u16 ldsB[BN * 64];
  const int t = threadIdx.x;
  const int lane = t & 63;
  const int w = t >> 6;
  const int m0 = blockIdx.x * BM;
  const int n0 = blockIdx.y * BN;
  const int kOff = blockIdx.z * KZ;
  const int Kloc = min(KZ, K - kOff);
  const int wm = w / WGN, wn = w % WGN;
  const int sr = t >> 3;          // staging row within 32-row group
  const int sk = (t & 7) * 8;     // staging k col (elements)

  if (zstride) Cf += (long)blockIdx.z * zstride;

  const u16* arow[AISS];
#pragma unroll
  for (int j = 0; j < AISS; ++j) {
    int r = m0 + j * 32 + sr;
    long rr = GATHER ? (long)idx[r] : (long)r;
    arow[j] = A + rr * (long)lda + sk + kOff;
  }
  const u16* brow[BISS];
#pragma unroll
  for (int j = 0; j < BISS; ++j)
    brow[j] = Bt + (long)(n0 + j * 32 + sr) * ldb + sk + kOff;

  f32x4 acc[AF][BF];
#pragma unroll
  for (int i = 0; i < AF; ++i)
#pragma unroll
    for (int j = 0; j < BF; ++j)
      acc[i][j] = (f32x4){0.f, 0.f, 0.f, 0.f};

  for (int k0 = 0; k0 < Kloc; k0 += 64) {
#pragma unroll
    for (int j = 0; j < AISS; ++j)
      gld_lds16(arow[j] + k0, &ldsA[(j * 32 + w * 8) * 64]);
#pragma unroll
    for (int j = 0; j < BISS; ++j)
      gld_lds16(brow[j] + k0, &ldsB[(j * 32 + w * 8) * 64]);
    __syncthreads();
#pragma unroll
    for (int k2 = 0; k2 < 64; k2 += 32) {
      bf16x8 af[AF], bfv[BF];
#pragma unroll
      for (int i = 0; i < AF; ++i)
        af[i] = *(const bf16x8*)&ldsA[(wm * WM + i * 16 + (lane & 15)) * 64 + k2 + (lane >> 4) * 8];
#pragma unroll
      for (int i = 0; i < BF; ++i)
        bfv[i] = *(const bf16x8*)&ldsB[(wn * WN + i * 16 + (lane & 15)) * 64 + k2 + (lane >> 4) * 8];
#pragma unroll
      for (int i = 0; i < AF; ++i)
#pragma unroll
        for (int j = 0; j < BF; ++j)
          acc[i][j] = __builtin_amdgcn_mfma_f32_16x16x32_bf16(af[i], bfv[j], acc[i][j], 0, 0, 0);
    }
    __syncthreads();
  }

  const int er = (lane >> 4) * 4;
  const int ecn = lane & 15;
#pragma unroll
  for (int i = 0; i < AF; ++i)
#pragma unroll
    for (int j = 0; j < BF; ++j)
#pragma unroll
      for (int r = 0; r < 4; ++r) {
        long gm = m0 + wm * WM + i * 16 + er + r;
        long gn = n0 + wn * WN + j * 16 + ecn;
        float v = acc[i][j][r];
        if (bias) v += bias[gn];
        if (rowscale) v *= rowscale[gm];
        if (relu) v = fmaxf(v, 0.f);
        if (Cb) Cb[gm * N + gn] = f2b(v);
        else    Cf[gm * N + gn] = v;
      }
}

// dual-instance 64x128 bf16 GEMM (z selects params): hs = rowscale[m]*(A@Bt^T)
__global__ void __launch_bounds__(256, 3)
gemm_dual(const u16* __restrict__ A0, const u16* __restrict__ A1, int lda,
          const u16* __restrict__ B0, const u16* __restrict__ B1, int ldb,
          int N, int K,
          const float* __restrict__ rs0, const float* __restrict__ rs1,
          u16* __restrict__ C0, u16* __restrict__ C1)
{
  const u16* A = blockIdx.z ? A1 : A0;
  const u16* Bt = blockIdx.z ? B1 : B0;
  const float* rowscale = blockIdx.z ? rs1 : rs0;
  u16* Cb = blockIdx.z ? C1 : C0;
  __shared__ __align__(16) u16 ldsA[64 * 64];
  __shared__ __align__(16) u16 ldsB[128 * 64];
  const int t = threadIdx.x;
  const int lane = t & 63;
  const int w = t >> 6;
  const int m0 = blockIdx.x * 64;
  const int n0 = blockIdx.y * 128;
  const int wm = w / 2, wn = w % 2;
  const int sr = t >> 3, sk = (t & 7) * 8;

  const u16* arow[2];
#pragma unroll
  for (int j = 0; j < 2; ++j)
    arow[j] = A + (long)(m0 + j * 32 + sr) * lda + sk;
  const u16* brow[4];
#pragma unroll
  for (int j = 0; j < 4; ++j)
    brow[j] = Bt + (long)(n0 + j * 32 + sr) * ldb + sk;

  f32x4 acc[2][4];
#pragma unroll
  for (int i = 0; i < 2; ++i)
#pragma unroll
    for (int j = 0; j < 4; ++j)
      acc[i][j] = (f32x4){0.f, 0.f, 0.f, 0.f};

  for (int k0 = 0; k0 < K; k0 += 64) {
#pragma unroll
    for (int j = 0; j < 2; ++j)
      gld_lds16(arow[j] + k0, &ldsA[(j * 32 + w * 8) * 64]);
#pragma unroll
    for (int j = 0; j < 4; ++j)
      gld_lds16(brow[j] + k0, &ldsB[(j * 32 + w * 8) * 64]);
    __syncthreads();
#pragma unroll
    for (int k2 = 0; k2 < 64; k2 += 32) {
      bf16x8 af[2], bfv[4];
#pragma unroll
      for (int i = 0; i < 2; ++i)
        af[i] = *(const bf16x8*)&ldsA[(wm * 32 + i * 16 + (lane & 15)) * 64 + k2 + (lane >> 4) * 8];
#pragma unroll
      for (int i = 0; i < 4; ++i)
        bfv[i] = *(const bf16x8*)&ldsB[(wn * 64 + i * 16 + (lane & 15)) * 64 + k2 + (lane >> 4) * 8];
#pragma unroll
      for (int i = 0; i < 2; ++i)
#pragma unroll
        for (int j = 0; j < 4; ++j)
          acc[i][j] = __builtin_amdgcn_mfma_f32_16x16x32_bf16(af[i], bfv[j], acc[i][j], 0, 0, 0);
    }
    __syncthreads();
  }

  const int er = (lane >> 4) * 4;
  const int ecn = lane & 15;
#pragma unroll
  for (int i = 0; i < 2; ++i)
#pragma unroll
    for (int j = 0; j < 4; ++j)
#pragma unroll
      for (int r = 0; r < 4; ++r) {
        long gm = m0 + wm * 32 + i * 16 + er + r;
        long gn = n0 + wn * 64 + j * 16 + ecn;
        Cb[gm * N + gn] = f2b(acc[i][j][r] * rowscale[gm]);
      }
}

// ---------------------------------------------------------------------------
// fp32-A GEMM (affinity rows, gathered): C[m,n] = sum_k A[idx(m),k]*Bt[n,k]
// split-K partials. BM=64, BN=256, A converted fp32->bf16 in-register.
// ---------------------------------------------------------------------------
__global__ void __launch_bounds__(256, 3)
gemm_a32g(const float* __restrict__ A, int lda,
          const u16* __restrict__ Bt, int ldb,
          int N, int KZ,
          const int* __restrict__ idx,
          float* __restrict__ Cf, long zstride)
{
  constexpr int AF = 2, BF = 8, WGN = 2;
  __shared__ __align__(16) u16 ldsA[64 * 72];
  __shared__ __align__(16) u16 ldsB[256 * 64];
  const int t = threadIdx.x;
  const int lane = t & 63;
  const int w = t >> 6;
  const int m0 = blockIdx.x * 64;
  const int n0 = blockIdx.y * 256;
  const int kOff = blockIdx.z * KZ;
  const int wm = w / WGN, wn = w % WGN;
  const int sr = t >> 3;
  const int sk = (t & 7) * 8;

  Cf += (long)blockIdx.z * zstride;

  const u16* brow[8];
#pragma unroll
  for (int j = 0; j < 8; ++j)
    brow[j] = Bt + (long)(n0 + j * 32 + sr) * ldb + sk + kOff;

  int r = m0 + (t >> 2);
  long rowsel = idx ? (long)idx[r] : (long)r;
  const float* ar_direct = A + rowsel * (long)lda + (t & 3) * 16 + kOff;

  f32x4 acc[AF][BF];
#pragma unroll
  for (int i = 0; i < AF; ++i)
#pragma unroll
    for (int j = 0; j < BF; ++j)
      acc[i][j] = (f32x4){0.f, 0.f, 0.f, 0.f};

  for (int k0 = 0; k0 < KZ; k0 += 64) {
#pragma unroll
    for (int j = 0; j < 8; ++j)
      gld_lds16(brow[j] + k0, &ldsB[(j * 32 + w * 8) * 64]);

    const float4* src = (const float4*)(ar_direct + k0);
    float4 v0 = src[0], v1 = src[1], v2 = src[2], v3 = src[3];
    u16x8 ua, ub;
    ua[0] = f2b(v0.x); ua[1] = f2b(v0.y); ua[2] = f2b(v0.z); ua[3] = f2b(v0.w);
    ua[4] = f2b(v1.x); ua[5] = f2b(v1.y); ua[6] = f2b(v1.z); ua[7] = f2b(v1.w);
    ub[0] = f2b(v2.x); ub[1] = f2b(v2.y); ub[2] = f2b(v2.z); ub[3] = f2b(v2.w);
    ub[4] = f2b(v3.x); ub[5] = f2b(v3.y); ub[6] = f2b(v3.z); ub[7] = f2b(v3.w);
    int ro = (t >> 2) * 72 + (t & 3) * 16;
    *(u16x8*)&ldsA[ro] = ua;
    *(u16x8*)&ldsA[ro + 8] = ub;
    __syncthreads();
#pragma unroll
    for (int k2 = 0; k2 < 64; k2 += 32) {
      bf16x8 af[AF], bfv[BF];
#pragma unroll
      for (int i = 0; i < AF; ++i)
        af[i] = *(const bf16x8*)&ldsA[(wm * 32 + i * 16 + (lane & 15)) * 72 + k2 + (lane >> 4) * 8];
#pragma unroll
      for (int i = 0; i < BF; ++i)
        bfv[i] = *(const bf16x8*)&ldsB[(wn * 128 + i * 16 + (lane & 15)) * 64 + k2 + (lane >> 4) * 8];
#pragma unroll
      for (int i = 0; i < AF; ++i)
#pragma unroll
        for (int j = 0; j < BF; ++j)
          acc[i][j] = __builtin_amdgcn_mfma_f32_16x16x32_bf16(af[i], bfv[j], acc[i][j], 0, 0, 0);
    }
    __syncthreads();
  }

  const int er = (lane >> 4) * 4;
  const int ecn = lane & 15;
#pragma unroll
  for (int i = 0; i < AF; ++i)
#pragma unroll
    for (int j = 0; j < BF; ++j)
#pragma unroll
      for (int rr2 = 0; rr2 < 4; ++rr2) {
        long gm = m0 + wm * 32 + i * 16 + er + rr2;
        long gn = n0 + wn * 128 + j * 16 + ecn;
        Cf[gm * N + gn] = acc[i][j][rr2];
      }
}

// z=0: sum 4 parts p1 -> o1 ; z=1: sum 2 parts p2 -> o2  (n floats each)
__global__ void reduce_both(const float* __restrict__ p1, const float* __restrict__ p2,
                            long n, float* __restrict__ o1, float* __restrict__ o2) {
  long i = ((long)blockIdx.x * 256 + threadIdx.x) * 4;
  if (i >= n) return;
  if (blockIdx.z == 0) {
    float4 a = *(const float4*)&p1[i];
    for (int z = 1; z < 4; ++z) {
      float4 b = *(const float4*)&p1[(long)z * n + i];
      a.x += b.x; a.y += b.y; a.z += b.z; a.w += b.w;
    }
    *(float4*)&o1[i] = a;
  } else {
    float4 a = *(const float4*)&p2[i];
    float4 b = *(const float4*)&p2[n + i];
    a.x += b.x; a.y += b.y; a.z += b.z; a.w += b.w;
    *(float4*)&o2[i] = a;
  }
}

// h1 = p[0] + p[1] + bias, plus BN column stats. grid (4, 64), cols=1024, 64 rows/blk
__global__ void reduce_h1_stats(const float* __restrict__ p, const float* __restrict__ bias,
                                float* __restrict__ h1,
                                float* __restrict__ sum, float* __restrict__ sq) {
  int c = blockIdx.x * 256 + threadIdx.x;
  int r0 = blockIdx.y * 64;
  const long n = (long)BBN * 1024;
  float b = bias[c];
  float s = 0.f, q = 0.f;
  for (int r = r0; r < r0 + 64; ++r) {
    long o = (long)r * 1024 + c;
    float v = p[o] + p[n + o] + b;
    h1[o] = v;
    s += v; q += v * v;
  }
  atomicAdd(&sum[c], s);
  atomicAdd(&sq[c], q);
}

// ---------------------------------------------------------------------------
// transpose-convert: affinity fp32 [8192 x 8192] -> affT bf16 [8192 x 8192]
// ---------------------------------------------------------------------------
__global__ void __launch_bounds__(256)
transcvt(const float* __restrict__ in, u16* __restrict__ out) {
  __shared__ float tile[64][65];
  const int t = threadIdx.x;
  const int r0 = blockIdx.x * 64, c0 = blockIdx.y * 64;
  {
    int rr = t >> 2, cb = (t & 3) * 16;
    const float4* src = (const float4*)&in[(long)(r0 + rr) * 8192 + c0 + cb];
    float4 a = src[0], b = src[1], c = src[2], d = src[3];
    float* dst = &tile[rr][cb];
    *(float4*)(dst) = a; *(float4*)(dst + 4) = b;
    *(float4*)(dst + 8) = c; *(float4*)(dst + 12) = d;
  }
  __syncthreads();
  {
    int cc = t >> 2, rb = (t & 3) * 16;
    u16x8 ua, ub;
#pragma unroll
    for (int j = 0; j < 8; ++j) {
      ua[j] = f2b(tile[rb + j][cc]);
      ub[j] = f2b(tile[rb + 8 + j][cc]);
    }
    u16* dst = &out[(long)(c0 + cc) * 8192 + r0 + rb];
    *(u16x8*)dst = ua;
    *(u16x8*)(dst + 8) = ub;
  }
}

// ---------------------------------------------------------------------------
// dual split-precision GEMM: C = relu(A_f32 @ Bt^T + bias), z selects instance
// ---------------------------------------------------------------------------
__global__ void __launch_bounds__(256, 3)
gemm_sp2(const float* __restrict__ A0, const float* __restrict__ A1, int lda,
         const u16* __restrict__ B0, const u16* __restrict__ B1, int ldb,
         int N, int K,
         const float* __restrict__ b0p, const float* __restrict__ b1p,
         float* __restrict__ C0, float* __restrict__ C1)
{
  const float* A = blockIdx.z ? A1 : A0;
  const u16* Bt = blockIdx.z ? B1 : B0;
  const float* bias = blockIdx.z ? b1p : b0p;
  float* Cf = blockIdx.z ? C1 : C0;
  __shared__ __align__(16) u16 ldsAh[64 * 64];
  __shared__ __align__(16) u16 ldsAl[64 * 64];
  __shared__ __align__(16) u16 ldsB[64 * 64];
  const int t = threadIdx.x, lane = t & 63, w = t >> 6;
  const int m0 = blockIdx.x * 64, n0 = blockIdx.y * 64;
  const int wm = w >> 1, wn = w & 1;
  const int sr = t >> 3, sk = (t & 7) * 8;
  const int ar = t >> 2;
  const int ak = (t & 3) * 16;
  const float* Ap = A + (long)(m0 + ar) * lda + ak;
  const u16* brow[2];
#pragma unroll
  for (int j = 0; j < 2; ++j)
    brow[j] = Bt + (long)(n0 + j * 32 + sr) * ldb + sk;

  f32x4 acc[2][2];
#pragma unroll
  for (int i = 0; i < 2; ++i)
#pragma unroll
    for (int j = 0; j < 2; ++j)
      acc[i][j] = (f32x4){0.f, 0.f, 0.f, 0.f};

  for (int k0 = 0; k0 < K; k0 += 64) {
#pragma unroll
    for (int j = 0; j < 2; ++j)
      gld_lds16(brow[j] + k0, &ldsB[(j * 32 + w * 8) * 64]);
    const float4* src = (const float4*)(Ap + k0);
    float4 v0 = src[0], v1 = src[1], v2 = src[2], v3 = src[3];
    float f[16] = {v0.x, v0.y, v0.z, v0.w, v1.x, v1.y, v1.z, v1.w,
                   v2.x, v2.y, v2.z, v2.w, v3.x, v3.y, v3.z, v3.w};
    u16x8 h0, h1v, l0, l1v;
#pragma unroll
    for (int i = 0; i < 8; ++i) {
      u16 h = f2b(f[i]);       h0[i] = h;  l0[i] = f2b(f[i] - b2f(h));
      u16 g = f2b(f[8 + i]);   h1v[i] = g; l1v[i] = f2b(f[8 + i] - b2f(g));
    }
    *(u16x8*)&ldsAh[ar * 64 + ak] = h0;
    *(u16x8*)&ldsAh[ar * 64 + ak + 8] = h1v;
    *(u16x8*)&ldsAl[ar * 64 + ak] = l0;
    *(u16x8*)&ldsAl[ar * 64 + ak + 8] = l1v;
    __syncthreads();
#pragma unroll
    for (int k2 = 0; k2 < 64; k2 += 32) {
      bf16x8 ah[2], al[2], bv[2];
#pragma unroll
      for (int i = 0; i < 2; ++i) {
        int off = (wm * 32 + i * 16 + (lane & 15)) * 64 + k2 + (lane >> 4) * 8;
        ah[i] = *(const bf16x8*)&ldsAh[off];
        al[i] = *(const bf16x8*)&ldsAl[off];
      }
#pragma unroll
      for (int i = 0; i < 2; ++i)
        bv[i] = *(const bf16x8*)&ldsB[(wn * 32 + i * 16 + (lane & 15)) * 64 + k2 + (lane >> 4) * 8];
#pragma unroll
      for (int i = 0; i < 2; ++i)
#pragma unroll
        for (int j = 0; j < 2; ++j) {
          acc[i][j] = __builtin_amdgcn_mfma_f32_16x16x32_bf16(ah[i], bv[j], acc[i][j], 0, 0, 0);
          acc[i][j] = __builtin_amdgcn_mfma_f32_16x16x32_bf16(al[i], bv[j], acc[i][j], 0, 0, 0);
        }
    }
    __syncthreads();
  }

  const int er = (lane >> 4) * 4;
  const int ecn = lane & 15;
#pragma unroll
  for (int i = 0; i < 2; ++i)
#pragma unroll
    for (int j = 0; j < 2; ++j)
#pragma unroll
      for (int r = 0; r < 4; ++r) {
        long gm = m0 + wm * 32 + i * 16 + er + r;
        long gn = n0 + wn * 32 + j * 16 + ecn;
        float v = acc[i][j][r] + bias[gn];
        Cf[gm * N + gn] = fmaxf(v, 0.f);
      }
}

// ---------------------------------------------------------------------------
// small kernels
// ---------------------------------------------------------------------------
// z selects (src,dst) pair; n elements each
__global__ void cvt2(const float* __restrict__ x0, u16* __restrict__ y0,
                     const float* __restrict__ x1, u16* __restrict__ y1, long n) {
  const float* x = blockIdx.z ? x1 : x0;
  u16* y = blockIdx.z ? y1 : y0;
  long i = ((long)blockIdx.x * 256 + threadIdx.x) * 4;
  if (i < n) {
    float4 v = *(const float4*)&x[i];
    u16 a = f2b(v.x), b = f2b(v.y), c = f2b(v.z), d = f2b(v.w);
    *(uint2*)&y[i] = make_uint2((u32)a | ((u32)b << 16), (u32)c | ((u32)d << 16));
  }
}

// merged weight transposes: 6 segments, linear block search
struct WtSeg { const float* in; u16* out; int R, C, Rpad, base, tx; };
__global__ void wtrans_all(WtSeg s0, WtSeg s1, WtSeg s2, WtSeg s3, WtSeg s4, WtSeg s5) {
  __shared__ float tile[32][33];
  WtSeg s;
  int b = blockIdx.x;
  if      (b >= s5.base) s = s5;
  else if (b >= s4.base) s = s4;
  else if (b >= s3.base) s = s3;
  else if (b >= s2.base) s = s2;
  else if (b >= s1.base) s = s1;
  else                   s = s0;
  int rel = b - s.base;
  int r0 = (rel % s.tx) * 32, c0 = (rel / s.tx) * 32;
  int tx = threadIdx.x & 31, ty = threadIdx.x >> 5;
  for (int j = 0; j < 32; j += 8) {
    int r = r0 + ty + j, c = c0 + tx;
    tile[ty + j][tx] = (r < s.R && c < s.C) ? s.in[(long)r * s.C + c] : 0.f;
  }
  __syncthreads();
  for (int j = 0; j < 32; j += 8) {
    int c = c0 + ty + j, r = r0 + tx;
    if (c < s.C && r < s.Rpad) s.out[(long)c * s.Rpad + r] = f2b(tile[tx][ty + j]);
  }
}

// dual bf16 transpose: z selects; in [R x C] -> out [C x R]
__global__ void btrans2(const u16* __restrict__ i0, u16* __restrict__ o0,
                        const u16* __restrict__ i1, u16* __restrict__ o1,
                        int R, int C) {
  const u16* in = blockIdx.z ? i1 : i0;
  u16* out = blockIdx.z ? o1 : o0;
  __shared__ u16 tile[32][34];
  int r0 = blockIdx.x * 32, c0 = blockIdx.y * 32;
  int tx = threadIdx.x & 31, ty = threadIdx.x >> 5;
  for (int j = 0; j < 32; j += 8)
    tile[ty + j][tx] = in[(long)(r0 + ty + j) * C + c0 + tx];
  __syncthreads();
  for (int j = 0; j < 32; j += 8)
    out[(long)(c0 + ty + j) * R + r0 + tx] = tile[tx][ty + j];
}

__global__ void edge_deg2(const int* __restrict__ ei_a, const float* __restrict__ ew_a,
                          const int* __restrict__ ei_b, const float* __restrict__ ew_b,
                          int E, float* degw_a, int* cnt_a,
                          float* degw_b, int* cnt_b) {
  int e = blockIdx.x * 256 + threadIdx.x;
  if (e >= E) return;
  const int* ei = blockIdx.y ? ei_b : ei_a;
  const float* ew = blockIdx.y ? ew_b : ew_a;
  float* degw = blockIdx.y ? degw_b : degw_a;
  int* cnt = blockIdx.y ? cnt_b : cnt_a;
  int dst = ei[E + e];
  atomicAdd(&degw[dst], ew[e]);
  atomicAdd(&cnt[dst], 1);
}

__global__ void scan_dinv(const int* __restrict__ cnt_a, int* rowptr_a, int* cursor_a,
                          const float* __restrict__ degw_a, float* dinv_a,
                          const int* __restrict__ cnt_b, int* rowptr_b, int* cursor_b,
                          const float* __restrict__ degw_b, float* dinv_b) {
  const int* cnt = blockIdx.x ? cnt_b : cnt_a;
  int* rowptr = blockIdx.x ? rowptr_b : rowptr_a;
  int* cursor = blockIdx.x ? cursor_b : cursor_a;
  const float* degw = blockIdx.x ? degw_b : degw_a;
  float* dinv = blockIdx.x ? dinv_b : dinv_a;
  __shared__ int lds[256];
  int t = threadIdx.x;
  int c0 = t * 32;
  int loc[32];
  int s = 0;
#pragma unroll
  for (int i = 0; i < 32; ++i) { loc[i] = cnt[c0 + i]; s += loc[i]; }
  lds[t] = s;
  __syncthreads();
  for (int off = 1; off < 256; off <<= 1) {
    int add = (t >= off) ? lds[t - off] : 0;
    __syncthreads();
    lds[t] += add;
    __syncthreads();
  }
  int run = lds[t] - s;
#pragma unroll
  for (int i = 0; i < 32; ++i) {
    rowptr[c0 + i] = run;
    cursor[c0 + i] = run;
    run += loc[i];
  }
  if (t == 255) rowptr[8192] = run;
#pragma unroll
  for (int i = 0; i < 32; ++i)
    dinv[c0 + i] = rsqrtf(degw[c0 + i] + 1.0f);
}

__global__ void edge_scatter2(const int* __restrict__ ei_a, const float* __restrict__ ew_a,
                              const int* __restrict__ ei_b, const float* __restrict__ ew_b,
                              int E, int* cursor_a, int2* edges_a,
                              int* cursor_b, int2* edges_b) {
  int e = blockIdx.x * 256 + threadIdx.x;
  if (e >= E) return;
  const int* ei = blockIdx.y ? ei_b : ei_a;
  const float* ew = blockIdx.y ? ew_b : ew_a;
  int* cursor = blockIdx.y ? cursor_b : cursor_a;
  int2* edges = blockIdx.y ? edges_b : edges_a;
  int src = ei[e], dst = ei[E + e];
  int pos = atomicAdd(&cursor[dst], 1);
  edges[pos] = make_int2(src, __float_as_int(ew[e]));
}

// merged aggregation: blocks [0,8192) -> graph a, [8192,16384) -> graph b
__global__ void agg2(const u16* __restrict__ hs_a, const int* __restrict__ rp_a,
                     const int2* __restrict__ ed_a, const float* __restrict__ di_a,
                     const float* __restrict__ bi_a, u16* __restrict__ out_a,
                     const u16* __restrict__ hs_b, const int* __restrict__ rp_b,
                     const int2* __restrict__ ed_b, const float* __restrict__ di_b,
                     const float* __restrict__ bi_b, u16* __restrict__ out_b) {
  const int gsel = blockIdx.x >> 13;
  const int i = blockIdx.x & 8191;
  const u16* hs = gsel ? hs_b : hs_a;
  const int* rowptr = gsel ? rp_b : rp_a;
  const int2* edges = gsel ? ed_b : ed_a;
  const float* dinv = gsel ? di_b : di_a;
  const float* bias = gsel ? bi_b : bi_a;
  u16* out = gsel ? out_b : out_a;
  const int t = threadIdx.x;
  const u32* base = (const u32*)hs;
  u32 hv = base[i * 256 + t];
  float a0 = b2f((u16)(hv & 0xffff));
  float a1 = b2f((u16)(hv >> 16));
  int s = rowptr[i], e = rowptr[i + 1];
  int p = s;
  for (; p + 4 <= e; p += 4) {
    int2 e0 = edges[p], e1 = edges[p + 1], e2 = edges[p + 2], e3 = edges[p + 3];
    u32 v0 = base[(long)e0.x * 256 + t];
    u32 v1 = base[(long)e1.x * 256 + t];
    u32 v2 = base[(long)e2.x * 256 + t];
    u32 v3 = base[(long)e3.x * 256 + t];
    float w0 = __int_as_float(e0.y), w1 = __int_as_float(e1.y);
    float w2 = __int_as_float(e2.y), w3 = __int_as_float(e3.y);
    a0 += w0 * b2f((u16)(v0 & 0xffff)); a1 += w0 * b2f((u16)(v0 >> 16));
    a0 += w1 * b2f((u16)(v1 & 0xffff)); a1 += w1 * b2f((u16)(v1 >> 16));
    a0 += w2 * b2f((u16)(v2 & 0xffff)); a1 += w2 * b2f((u16)(v2 >> 16));
    a0 += w3 * b2f((u16)(v3 & 0xffff)); a1 += w3 * b2f((u16)(v3 >> 16));
  }
  for (; p < e; ++p) {
    int2 ee = edges[p];
    u32 v = base[(long)ee.x * 256 + t];
    float ww = __int_as_float(ee.y);
    a0 += ww * b2f((u16)(v & 0xffff));
    a1 += ww * b2f((u16)(v >> 16));
  }
  float di = dinv[i];
  float o0 = bias[2 * t] + di * a0;
  float o1 = bias[2 * t + 1] + di * a1;
  o0 = (o0 >= 0.f) ? o0 : 0.01f * o0;
  o1 = (o1 >= 0.f) ? o1 : 0.01f * o1;
  ((u32*)out)[i * 256 + t] = (u32)f2b(o0) | ((u32)f2b(o1) << 16);
}

__global__ void colsum_all(const float* __restrict__ d_vecs, const float* __restrict__ p_emb,
                           const u16* __restrict__ ec, const u16* __restrict__ gos,
                           const float* __restrict__ t1, const float* __restrict__ t2,
                           const int* __restrict__ didx, const int* __restrict__ pidx,
                           float* __restrict__ out) {
  int c = blockIdx.x * 256 + threadIdx.x;
  if (c >= 3372) return;
  int r0 = blockIdx.y * 128;
  float s = 0.f;
  if (c < 300) {
    for (int r = r0; r < r0 + 128; ++r) s += d_vecs[(long)r * 300 + c];
  } else if (c < 1324) {
    int cc = c - 300;
    for (int r = r0; r < r0 + 128; ++r) s += p_emb[(long)r * 1024 + cc];
  } else if (c < 1836) {
    int cc = c - 1324;
    for (int r = r0; r < r0 + 128; ++r) s += b2f(ec[(long)didx[r] * 512 + cc]);
  } else if (c < 2348) {
    int cc = c - 1836;
    for (int r = r0; r < r0 + 128; ++r) s += t1[(long)r * 512 + cc];
  } else if (c < 2860) {
    int cc = c - 2348;
    for (int r = r0; r < r0 + 128; ++r) s += b2f(gos[(long)pidx[r] * 512 + cc]);
  } else {
    int cc = c - 2860;
    for (int r = r0; r < r0 + 128; ++r) s += t2[(long)r * 512 + cc];
  }
  atomicAdd(&out[c], s);
}

__global__ void assemble(const float* __restrict__ d_vecs, const float* __restrict__ p_emb,
                         const u16* __restrict__ ec, const u16* __restrict__ gos,
                         const float* __restrict__ t1, const float* __restrict__ t2,
                         const int* __restrict__ didx, const int* __restrict__ pidx,
                         const float* __restrict__ cs, u16* __restrict__ feat) {
  const float is = 1.f / 4096.f;
  int b = blockIdx.x;
  int t = threadIdx.x;
  long ob = (long)b * KPAD;
  int di = didx[b], pi = pidx[b];
  for (int j = t; j < 300; j += 256)
    feat[ob + j] = f2b(d_vecs[(long)b * 300 + j] - cs[j] * is);
  for (int j = t; j < 1024; j += 256)
    feat[ob + 300 + j] = f2b(p_emb[(long)b * 1024 + j] - cs[300 + j] * is);
  for (int j = t; j < 512; j += 256) {
    feat[ob + 1324 + j] = f2b(b2f(ec[(long)di * 512 + j]) - cs[1324 + j] * is);
    feat[ob + 1836 + j] = f2b(t1[(long)b * 512 + j] - cs[1836 + j] * is);
    feat[ob + 2348 + j] = f2b(b2f(gos[(long)pi * 512 + j]) - cs[2348 + j] * is);
    feat[ob + 2860 + j] = f2b(t2[(long)b * 512 + j] - cs[2860 + j] * is);
  }
  for (int j = t; j < 20; j += 256) feat[ob + 3372 + j] = 0;
}

__global__ void bn_stats(const float* __restrict__ x, int N,
                         float* __restrict__ sum, float* __restrict__ sumsq) {
  int r0 = blockIdx.x * 32;
  int t = threadIdx.x;
  for (int c = t; c < N; c += 256) {
    float s = 0.f, q = 0.f;
    for (int r = 0; r < 32; ++r) {
      float v = x[(long)(r0 + r) * N + c];
      s += v; q += v * v;
    }
    atomicAdd(&sum[c], s);
    atomicAdd(&sumsq[c], q);
  }
}

// vectorized x4 BN apply -> bf16
__global__ void bn_apply4(const float* __restrict__ x, int M, long total, int nmask,
                          const float* __restrict__ sum, const float* __restrict__ sumsq,
                          const float* __restrict__ g, const float* __restrict__ be,
                          u16* __restrict__ y) {
  long i = ((long)blockIdx.x * 256 + threadIdx.x) * 4;
  if (i >= total) return;
  float4 v = *(const float4*)&x[i];
  int c = (int)(i & nmask);
  float Mi = 1.f / (float)M;
  u16 o[4];
  float vv[4] = {v.x, v.y, v.z, v.w};
#pragma unroll
  for (int j = 0; j < 4; ++j) {
    float m = sum[c + j] * Mi;
    float var = sumsq[c + j] * Mi - m * m;
    float sc = g[c + j] * rsqrtf(var + 1e-5f);
    float sh = be[c + j] - m * sc;
    o[j] = f2b(fmaxf(vv[j] * sc + sh, 0.f));
  }
  *(uint2*)&y[i] = make_uint2((u32)o[0] | ((u32)o[1] << 16), (u32)o[2] | ((u32)o[3] << 16));
}

// fused BN2 + final dot: y[row] = sum_c relu(bn(h2[row,c])) * w3[c] + b3
__global__ void bn_final(const float* __restrict__ h2,
                         const float* __restrict__ sum, const float* __restrict__ sq,
                         const float* __restrict__ g, const float* __restrict__ be,
                         const float* __restrict__ w3, const float* __restrict__ b3,
                         float* __restrict__ y) {
  int wv = threadIdx.x >> 6, lane = threadIdx.x & 63;
  int row = blockIdx.x * 4 + wv;
  float4 v = *(const float4*)&h2[(long)row * 256 + lane * 4];
  float vv[4] = {v.x, v.y, v.z, v.w};
  const float Mi = 1.f / 4096.f;
  float acc = 0.f;
#pragma unroll
  for (int j = 0; j < 4; ++j) {
    int c = lane * 4 + j;
    float m = sum[c] * Mi;
    float var = sq[c] * Mi - m * m;
    float sc = g[c] * rsqrtf(var + 1e-5f);
    float sh = be[c] - m * sc;
    float h = fmaxf(vv[j] * sc + sh, 0.f);
    acc += h * w3[c];
  }
  for (int off = 32; off; off >>= 1) acc += __shfl_down(acc, off);
  if (lane == 0) y[row] = acc + b3[0];
}

// ---------------------------------------------------------------------------
extern "C" void kernel_launch(void* const* d_in, const int* in_sizes, int n_in,
                              void* d_out, int out_size, void* d_ws, size_t ws_size,
                              hipStream_t stream) {
  (void)in_sizes; (void)n_in; (void)out_size; (void)ws_size;
  const int*   d_index  = (const int*)d_in[0];
  const int*   p_index  = (const int*)d_in[1];
  const float* d_vecs   = (const float*)d_in[2];
  const float* p_emb    = (const float*)d_in[3];
  const float* d_ecfps  = (const float*)d_in[4];
  const int*   d_ei     = (const int*)d_in[5];
  const float* d_ew     = (const float*)d_in[6];
  const float* p_gos    = (const float*)d_in[7];
  const int*   p_ei     = (const int*)d_in[8];
  const float* p_ew     = (const float*)d_in[9];
  const float* affinity = (const float*)d_in[10];
  const float* W_e  = (const float*)d_in[11];
  const float* b_e  = (const float*)d_in[12];
  const float* W_g  = (const float*)d_in[13];
  const float* b_g  = (const float*)d_in[14];
  const float* W1   = (const float*)d_in[15];
  const float* b1   = (const float*)d_in[16];
  const float* W2   = (const float*)d_in[17];
  const float* b2   = (const float*)d_in[18];
  const float* Wo1  = (const float*)d_in[19];
  const float* bo1  = (const float*)d_in[20];
  const float* g1   = (const float*)d_in[21];
  const float* be1  = (const float*)d_in[22];
  const float* Wo2  = (const float*)d_in[23];
  const float* bo2  = (const float*)d_in[24];
  const float* g2   = (const float*)d_in[25];
  const float* be2  = (const float*)d_in[26];
  const float* Wo3  = (const float*)d_in[27];
  const float* bo3  = (const float*)d_in[28];
  float* y_out = (float*)d_out;

  char* p = (char*)d_ws;
  auto alloc = [&](size_t bytes) -> char* {
    char* q = p;
    p += (bytes + 255) & ~(size_t)255;
    return q;
  };

  // zero-init block (one memset)
  char* zero_start = p;
  float* degw_e = (float*)alloc(NDN * 4);
  int*   cnt_e  = (int*)alloc(NDN * 4);
  float* degw_p = (float*)alloc(NPN * 4);
  int*   cnt_p  = (int*)alloc(NPN * 4);
  float* bnsum1 = (float*)alloc(1024 * 4);
  float* bnsq1  = (float*)alloc(1024 * 4);
  float* bnsum2 = (float*)alloc(256 * 4);
  float* bnsq2  = (float*)alloc(256 * 4);
  float* colsum = (float*)alloc(KPAD * 4);
  size_t zero_bytes = (size_t)(p - zero_start);

  float* dinv_e   = (float*)alloc(NDN * 4);
  float* dinv_p   = (float*)alloc(NPN * 4);
  int*   rowptr_e = (int*)alloc((NDN + 1) * 4);
  int*   cursor_e = (int*)alloc(NDN * 4);
  int*   rowptr_p = (int*)alloc((NPN + 1) * 4);
  int*   cursor_p = (int*)alloc(NPN * 4);
  int2*  edges_e  = (int2*)alloc((size_t)EDN * 8);
  int2*  edges_p  = (int2*)alloc((size_t)EPN * 8);
  u16* x_e_b  = (u16*)alloc((size_t)NDN * 1024 * 2);   // aliased: tmp1_f
  u16* x_g_b  = (u16*)alloc((size_t)NPN * 1024 * 2);   // aliased: tmp2_f
  u16* WeT    = (u16*)alloc((size_t)512 * 1024 * 2);
  u16* WgT    = (u16*)alloc((size_t)512 * 1024 * 2);
  u16* W1T    = (u16*)alloc((size_t)512 * 512 * 2);
  u16* W2T    = (u16*)alloc((size_t)512 * 512 * 2);
  u16* Wo1T   = (u16*)alloc((size_t)1024 * KPAD * 2);
  u16* Wo2T   = (u16*)alloc((size_t)256 * 1024 * 2);
  u16* hs_e   = (u16*)alloc((size_t)NDN * 512 * 2);    // aliased: t1_f
  u16* hs_g   = (u16*)alloc((size_t)NPN * 512 * 2);    // aliased: t2_f
  u16* ec_b   = (u16*)alloc((size_t)NDN * 512 * 2);
  u16* gos_b  = (u16*)alloc((size_t)NPN * 512 * 2);
  u16* ecT_b  = (u16*)alloc((size_t)512 * NDN * 2);
  u16* gosT_b = (u16*)alloc((size_t)512 * NPN * 2);
  u16* affT_b = (u16*)alloc((size_t)8192 * 8192 * 2);  // 128 MB
  u16* feat_b = (u16*)alloc((size_t)BBN * KPAD * 2);
  float* h1   = (float*)alloc((size_t)BBN * 1024 * 4);
  u16* h1n_b  = (u16*)alloc((size_t)BBN * 1024 * 2);
  float* h2   = (float*)alloc((size_t)BBN * 256 * 4);
  // split-K partials: partK = 4x(4096x512) == 2x(4096x1024); partK2 = 2x(4096x512)
  float* partK  = (float*)alloc((size_t)4 * BBN * 512 * 4);
  float* partK2 = (float*)alloc((size_t)2 * BBN * 512 * 4);

  float* tmp1_f = (float*)x_e_b;   // [4096 x 512] f32 (b-indexed)
  float* tmp2_f = (float*)x_g_b;   // [4096 x 512] f32 (b-indexed)
  float* t1_f   = (float*)hs_e;    // [4096 x 512] f32
  float* t2_f   = (float*)hs_g;

  hipMemsetAsync(zero_start, 0, zero_bytes, stream);

  // input conversions (merged)
  cvt2<<<dim3(8192, 1, 2), 256, 0, stream>>>(d_ecfps, x_e_b, p_gos, x_g_b, (long)NDN * 1024);
  {
    WtSeg s0{W_e,  WeT,  1024, 512,  1024, 0,                         32};
    WtSeg s1{W_g,  WgT,  1024, 512,  1024, 512,                       32};
    WtSeg s2{W1,   W1T,  512,  512,  512,  1024,                      16};
    WtSeg s3{W2,   W2T,  512,  512,  512,  1280,                      16};
    WtSeg s4{Wo1,  Wo1T, 3372, 1024, KPAD, 1536,                      106};
    WtSeg s5{Wo2,  Wo2T, 1024, 256,  1024, 1536 + 3392,               32};
    wtrans_all<<<1536 + 3392 + 256, 256, 0, stream>>>(s0, s1, s2, s3, s4, s5);
  }
  transcvt<<<dim3(128, 128), 256, 0, stream>>>(affinity, affT_b);

  // graph prep
  edge_deg2<<<dim3(EDN / 256, 2), 256, 0, stream>>>(d_ei, d_ew, p_ei, p_ew, EDN,
                                                    degw_e, cnt_e, degw_p, cnt_p);
  scan_dinv<<<2, 256, 0, stream>>>(cnt_e, rowptr_e, cursor_e, degw_e, dinv_e,
                                   cnt_p, rowptr_p, cursor_p, degw_p, dinv_p);
  edge_scatter2<<<dim3(EDN / 256, 2), 256, 0, stream>>>(d_ei, d_ew, p_ei, p_ew, EDN,
                                                        cursor_e, edges_e,
                                                        cursor_p, edges_p);

  // G1/G2 merged: hs = dinv[m] * (x @ W)
  gemm_dual<<<dim3(128, 4, 2), 256, 0, stream>>>(
      x_e_b, x_g_b, 1024, WeT, WgT, 1024, 512, 1024,
      dinv_e, dinv_p, hs_e, hs_g);

  // aggregation merged
  agg2<<<16384, 256, 0, stream>>>(hs_e, rowptr_e, edges_e, dinv_e, b_e, ec_b,
                                  hs_g, rowptr_p, edges_p, dinv_p, b_g, gos_b);

  // transposes merged
  btrans2<<<dim3(256, 16, 2), 256, 0, stream>>>(ec_b, ecT_b, gos_b, gosT_b, NDN, 512);

  // G3: tmp1 = affinity[d_index] @ gos  split-K=4
  gemm_a32g<<<dim3(64, 2, 4), 256, 0, stream>>>(
      affinity, 8192, gosT_b, 8192, 512, 2048, d_index, partK, (long)BBN * 512);
  // G4: tmp2 = (affinity^T)[p_index] @ ecfps  split-K=2
  gemm_bf16<64, 128, 32, 64, true><<<dim3(64, 4, 2), 256, 0, stream>>>(
      affT_b, 8192, ecT_b, 8192, 512, 8192, 4096, p_index,
      partK2, (u16*)nullptr, (long)BBN * 512,
      (const float*)nullptr, (const float*)nullptr, 0);
  reduce_both<<<dim3(2048, 1, 2), 256, 0, stream>>>(partK, partK2, (long)BBN * 512,
                                                    tmp1_f, tmp2_f);

  // G5/G6 merged: t = relu(tmp @ W + b)
  gemm_sp2<<<dim3(64, 8, 2), 256, 0, stream>>>(
      tmp1_f, tmp2_f, 512, W1T, W2T, 512, 512, 512, b1, b2, t1_f, t2_f);

  // centering sums + assembly
  colsum_all<<<dim3(14, 32), 256, 0, stream>>>(d_vecs, p_emb, ec_b, gos_b,
                                               t1_f, t2_f, d_index, p_index, colsum);
  assemble<<<BBN, 256, 0, stream>>>(d_vecs, p_emb, ec_b, gos_b, t1_f, t2_f,
                                    d_index, p_index, colsum, feat_b);

  // G7: h1 = feat_c @ Wo1 + bo1  split-K=2; reduce fused with BN1 stats
  gemm_bf16<64, 128, 32, 64, false><<<dim3(64, 8, 2), 256, 0, stream>>>(
      feat_b, KPAD, Wo1T, KPAD, 1024, KPAD, 1728, nullptr,
      partK, (u16*)nullptr, (long)BBN * 1024,
      (const float*)nullptr, (const float*)nullptr, 0);
  reduce_h1_stats<<<dim3(4, 64), 256, 0, stream>>>(partK, bo1, h1, bnsum1, bnsq1);
  bn_apply4<<<4096, 256, 0, stream>>>(h1, BBN, (long)BBN * 1024, 1023,
                                      bnsum1, bnsq1, g1, be1, h1n_b);

  // G8: h2 = h1n @ Wo2 + bo2
  gemm_bf16<64, 64, 32, 32, false><<<dim3(64, 4), 256, 0, stream>>>(
      h1n_b, 1024, Wo2T, 1024, 256, 1024, 1024, nullptr,
      h2, (u16*)nullptr, 0, bo2, (const float*)nullptr, 0);
  bn_stats<<<128, 256, 0, stream>>>(h2, 256, bnsum2, bnsq2);

  // fused BN2 + final dot
  bn_final<<<1024, 256, 0, stream>>>(h2, bnsum2, bnsq2, g2, be2, Wo3, bo3, y_out);
}